// Round 4
// baseline (950.017 us; speedup 1.0000x reference)
//
#include <hip/hip_runtime.h>
#include <hip/hip_bf16.h>

using u16 = unsigned short;
typedef __bf16 bf16x8_t __attribute__((ext_vector_type(8)));
typedef float    f32x4  __attribute__((ext_vector_type(4)));
typedef unsigned short u16x8 __attribute__((ext_vector_type(8)));

#define B_  64
#define L_  1024
#define TOT 65536
#define D_  512
#define H_  2048
#define NH_ 8

__device__ __forceinline__ float b2f(u16 x) {
    union { unsigned int i; float f; } v; v.i = ((unsigned int)x) << 16; return v.f;
}
__device__ __forceinline__ u16 f2b(float f) {
    union { float f; unsigned int i; } v; v.f = f;
    unsigned int i = v.i;
    unsigned int r = i + 0x7FFFu + ((i >> 16) & 1u);   // RNE
    return (u16)(r >> 16);
}

// ---------------- transpose + fp32->bf16 convert:  in[R][C] f32 -> out[C][R] bf16
__global__ __launch_bounds__(256) void transpose_cvt(const float* __restrict__ in,
                                                     u16* __restrict__ out, int R, int C) {
    __shared__ float tile[32][33];
    int c0 = blockIdx.x * 32, r0 = blockIdx.y * 32;
    int tx = threadIdx.x, ty = threadIdx.y;
    #pragma unroll
    for (int i = 0; i < 4; ++i)
        tile[ty + 8 * i][tx] = in[(size_t)(r0 + ty + 8 * i) * C + c0 + tx];
    __syncthreads();
    #pragma unroll
    for (int i = 0; i < 4; ++i)
        out[(size_t)(c0 + ty + 8 * i) * R + r0 + tx] = f2b(tile[tx][ty + 8 * i]);
}

// ---------------- qp = q @ Wq + bq   (512 outputs, 2 blocks)
__global__ __launch_bounds__(256) void qp_kernel(const float* __restrict__ q,
                                                 const float* __restrict__ Wq,
                                                 const float* __restrict__ bq,
                                                 float* __restrict__ qp) {
    __shared__ float qs[512];
    int tid = threadIdx.x;
    qs[tid] = q[tid]; qs[tid + 256] = q[tid + 256];
    __syncthreads();
    int j = blockIdx.x * 256 + tid;
    float acc = bq[j];
    for (int d = 0; d < 512; ++d) acc += qs[d] * Wq[(size_t)d * 512 + j];
    qp[j] = acc;
}

// ---------------- wke[d][h] = 0.125 * sum_j Wk[d, h*64+j]*qp[h*64+j];  cke[h] from bk
__global__ __launch_bounds__(256) void wke_kernel(const float* __restrict__ Wk,
                                                  const float* __restrict__ bk,
                                                  const float* __restrict__ qp,
                                                  float* __restrict__ wke,
                                                  float* __restrict__ cke) {
    __shared__ float qs[512];
    int tid = threadIdx.x;
    qs[tid] = qp[tid]; qs[tid + 256] = qp[tid + 256];
    __syncthreads();
    int d = blockIdx.x * 32 + (tid >> 3);
    int h = tid & 7;
    float s = 0.f;
    for (int j = 0; j < 64; ++j) s += Wk[(size_t)d * 512 + h * 64 + j] * qs[h * 64 + j];
    wke[d * 8 + h] = 0.125f * s;
    if (blockIdx.x == 0 && tid < 8) {
        float c = 0.f;
        for (int j = 0; j < 64; ++j) c += bk[tid * 64 + j] * qs[tid * 64 + j];
        cke[tid] = 0.125f * c;
    }
}

// ---------------- gather emb rows -> bf16 z chunk
__global__ __launch_bounds__(256) void embed_kernel(const int* __restrict__ idx,
                                                    const float* __restrict__ emb,
                                                    u16* __restrict__ z) {
    int u = blockIdx.x * 256 + threadIdx.x;   // one unit = 8 elements
    int t = u >> 6;                            // 64 units per 512-wide row
    int d0 = (u & 63) * 8;
    int row = idx[t];
    const float4* src = (const float4*)(emb + (size_t)row * 512 + d0);
    float4 a = src[0], b = src[1];
    u16x8 o;
    o[0] = f2b(a.x); o[1] = f2b(a.y); o[2] = f2b(a.z); o[3] = f2b(a.w);
    o[4] = f2b(b.x); o[5] = f2b(b.y); o[6] = f2b(b.z); o[7] = f2b(b.w);
    *(u16x8*)(z + (size_t)t * 512 + d0) = o;
}

// ---------------- bf16 GEMM, BK=64:  C[M,N] = act(A[M,K] @ Bt[N,K]^T + bias)
// XCD-aware 1D swizzle (all n-tiles of an m-row on one XCD) + LDS XOR swizzle
// (8 colgroups/row; ds_read_b128 spreads 2-way across banks = free).
// BK=64 halves barrier-drain count per MFMA vs BK=32: 32 MFMA (~155cyc)
// against one ~230cyc vmcnt(0) drain -> predicted MfmaUtil ~40%.
template <int RELU, int LNT>
__global__ __launch_bounds__(256) void gemm_bt(const u16* __restrict__ A,
                                               const u16* __restrict__ Bt,
                                               const float* __restrict__ bias,
                                               u16* __restrict__ C,
                                               int N, int K) {
    __shared__ __align__(16) u16 As[128 * 64];
    __shared__ __align__(16) u16 Bs[128 * 64];
    const int tid = threadIdx.x;
    const int id = blockIdx.x;
    const int xcd = id & 7, s = id >> 3;
    const int n_idx = s & ((1 << LNT) - 1);
    const int m_idx = xcd + 8 * (s >> LNT);
    const int m0 = m_idx * 128, n0 = n_idx * 128;
    const int lane = tid & 63, quad = lane >> 4, l15 = lane & 15;
    const int wave = tid >> 6, wm = wave >> 1, wn = wave & 1;

    f32x4 acc[4][4] = {};

    const int nK = K >> 6;
    for (int kt = 0; kt < nK; ++kt) {
        __syncthreads();
        const int kb = kt * 64;
        #pragma unroll
        for (int r = 0; r < 4; ++r) {
            int u = tid + r * 256;
            int row = u >> 3;
            int cg = (u & 7) ^ (row & 7);    // global colgroup stored in this LDS slot
            const u16* ga = A + (size_t)(m0 + row) * K + kb + cg * 8;
            __builtin_amdgcn_global_load_lds((const __attribute__((address_space(1))) void*)ga,
                                             (__attribute__((address_space(3))) void*)(&As[u * 8]),
                                             16, 0, 0);
            const u16* gb = Bt + (size_t)(n0 + row) * K + kb + cg * 8;
            __builtin_amdgcn_global_load_lds((const __attribute__((address_space(1))) void*)gb,
                                             (__attribute__((address_space(3))) void*)(&Bs[u * 8]),
                                             16, 0, 0);
        }
        __syncthreads();
        #pragma unroll
        for (int ks = 0; ks < 2; ++ks) {
            bf16x8_t af[4], bfr[4];
            #pragma unroll
            for (int mt = 0; mt < 4; ++mt) {
                int row = wm * 64 + mt * 16 + l15;
                int g = (ks * 4 + quad) ^ (row & 7);
                af[mt] = *(const bf16x8_t*)&As[row * 64 + g * 8];
            }
            #pragma unroll
            for (int nt = 0; nt < 4; ++nt) {
                int row = wn * 64 + nt * 16 + l15;
                int g = (ks * 4 + quad) ^ (row & 7);
                bfr[nt] = *(const bf16x8_t*)&Bs[row * 64 + g * 8];
            }
            #pragma unroll
            for (int mt = 0; mt < 4; ++mt)
                #pragma unroll
                for (int nt = 0; nt < 4; ++nt)
                    acc[mt][nt] = __builtin_amdgcn_mfma_f32_16x16x32_bf16(af[mt], bfr[nt],
                                                                          acc[mt][nt], 0, 0, 0);
        }
    }

    float bvv[4];
    #pragma unroll
    for (int nt = 0; nt < 4; ++nt) bvv[nt] = bias[n0 + wn * 64 + nt * 16 + l15];
    #pragma unroll
    for (int mt = 0; mt < 4; ++mt)
        #pragma unroll
        for (int nt = 0; nt < 4; ++nt)
            #pragma unroll
            for (int r = 0; r < 4; ++r) {
                int row = m0 + wm * 64 + mt * 16 + quad * 4 + r;
                int col = n0 + wn * 64 + nt * 16 + l15;
                float v = acc[mt][nt][r] + bvv[nt];
                if (RELU) v = fmaxf(v, 0.f);
                C[(size_t)row * N + col] = f2b(v);
            }
}

// ---------------- scores[b][h][l] = h[b,l,:] . wke[:,h] + cke[h]
__global__ __launch_bounds__(256) void score_kernel(const u16* __restrict__ h,
                                                    const float* __restrict__ wke,
                                                    const float* __restrict__ cke,
                                                    float* __restrict__ scb) {
    const int b = blockIdx.y, lc = blockIdx.x, tid = threadIdx.x;
    const int w = tid >> 6, lane = tid & 63;

    float wkr[8][8];
    #pragma unroll
    for (int j = 0; j < 8; ++j)
        #pragma unroll
        for (int hh = 0; hh < 8; ++hh) wkr[j][hh] = wke[(lane * 8 + j) * 8 + hh];
    float cr[8];
    #pragma unroll
    for (int hh = 0; hh < 8; ++hh) cr[hh] = cke[hh];

    const u16* hb = h + (size_t)b * 1024 * 512;

    #pragma unroll 2
    for (int i = 0; i < 16; ++i) {
        int l = lc * 64 + w * 16 + i;
        u16x8 hv = *(const u16x8*)(hb + (size_t)l * 512 + lane * 8);
        float s[8] = {0, 0, 0, 0, 0, 0, 0, 0};
        #pragma unroll
        for (int j = 0; j < 8; ++j) {
            float hf = b2f(hv[j]);
            #pragma unroll
            for (int hh = 0; hh < 8; ++hh) s[hh] += hf * wkr[j][hh];
        }
        #pragma unroll
        for (int hh = 0; hh < 8; ++hh) {
            float v = s[hh];
            for (int off = 32; off; off >>= 1) v += __shfl_xor(v, off, 64);
            if (lane == 0) scb[((size_t)b * 8 + hh) * 1024 + l] = v + cr[hh];
        }
    }
}

// ---------------- softmax over l for each (b,h); in-place on scb. grid 512.
__global__ __launch_bounds__(256) void softmax_kernel(float* __restrict__ scb) {
    __shared__ float red[8];
    const int bh = blockIdx.x, tid = threadIdx.x;
    const int w = tid >> 6, lane = tid & 63;
    float* p = scb + (size_t)bh * 1024;
    float4 v = ((float4*)p)[tid];
    float m = fmaxf(fmaxf(v.x, v.y), fmaxf(v.z, v.w));
    for (int off = 32; off; off >>= 1) m = fmaxf(m, __shfl_xor(m, off, 64));
    if (lane == 0) red[w] = m;
    __syncthreads();
    m = fmaxf(fmaxf(red[0], red[1]), fmaxf(red[2], red[3]));
    float4 e;
    e.x = __expf(v.x - m); e.y = __expf(v.y - m);
    e.z = __expf(v.z - m); e.w = __expf(v.w - m);
    float s = e.x + e.y + e.z + e.w;
    for (int off = 32; off; off >>= 1) s += __shfl_xor(s, off, 64);
    __syncthreads();
    if (lane == 0) red[4 + w] = s;
    __syncthreads();
    float inv = 1.f / (red[4] + red[5] + red[6] + red[7]);
    e.x *= inv; e.y *= inv; e.z *= inv; e.w *= inv;
    ((float4*)p)[tid] = e;
}

// ---------------- wave partials of u
__global__ __launch_bounds__(256) void wsum_kernel(const u16* __restrict__ h,
                                                   const float* __restrict__ scb,
                                                   float* __restrict__ pbuf) {
    __shared__ float as[8][256];
    const int b = blockIdx.y, c = blockIdx.x, tid = threadIdx.x;
    const int w = tid >> 6, lane = tid & 63;
    for (int i = tid; i < 2048; i += 256) {
        int hh = i >> 8, l = i & 255;
        as[hh][l] = scb[((size_t)b * 8 + hh) * 1024 + c * 256 + l];
    }
    __syncthreads();
    const u16* hb = h + ((size_t)b * 1024 + c * 256 + w * 64) * 512 + lane * 8;
    float acc[8][8] = {};
    for (int i = 0; i < 64; ++i) {
        u16x8 hv = *(const u16x8*)(hb + (size_t)i * 512);
        int l = w * 64 + i;
        float av[8];
        #pragma unroll
        for (int hh = 0; hh < 8; ++hh) av[hh] = as[hh][l];
        #pragma unroll
        for (int j = 0; j < 8; ++j) {
            float hf = b2f(hv[j]);
            #pragma unroll
            for (int hh = 0; hh < 8; ++hh) acc[hh][j] += av[hh] * hf;
        }
    }
    float* pw = pbuf + ((size_t)b * 16 + c * 4 + w) * 4096;
    #pragma unroll
    for (int hh = 0; hh < 8; ++hh) {
        float4 lo, hi;
        lo.x = acc[hh][0]; lo.y = acc[hh][1]; lo.z = acc[hh][2]; lo.w = acc[hh][3];
        hi.x = acc[hh][4]; hi.y = acc[hh][5]; hi.z = acc[hh][6]; hi.w = acc[hh][7];
        *(float4*)(pw + hh * 512 + lane * 8) = lo;
        *(float4*)(pw + hh * 512 + lane * 8 + 4) = hi;
    }
}

// ---------------- per-set: fold partials; ctx = u@Wv + bv; pooled = ctx@Wo + bo; LN -> y
__global__ __launch_bounds__(256) void pool_kernel(const float* __restrict__ pbuf,
                                                   const float* __restrict__ Wv,
                                                   const float* __restrict__ bv,
                                                   const float* __restrict__ Wo,
                                                   const float* __restrict__ bo,
                                                   const float* __restrict__ g,
                                                   const float* __restrict__ lb,
                                                   float* __restrict__ y) {
    __shared__ float us[8 * 512];
    __shared__ float ctx[512];
    __shared__ float red[8];
    __shared__ float stats[2];
    const int b = blockIdx.x, tid = threadIdx.x;
    for (int i = tid; i < 4096; i += 256) {
        float s = 0.f;
        #pragma unroll
        for (int c = 0; c < 16; ++c) s += pbuf[((size_t)b * 16 + c) * 4096 + i];
        us[i] = s;
    }
    __syncthreads();
    #pragma unroll
    for (int ph = 0; ph < 2; ++ph) {
        int e = tid + ph * 256;
        int hh = e >> 6;
        float acc = bv[e];
        for (int dd = 0; dd < 512; ++dd) acc += us[hh * 512 + dd] * Wv[(size_t)dd * 512 + e];
        ctx[e] = acc;
    }
    __syncthreads();
    float pv[2]; float psum = 0.f, psq = 0.f;
    #pragma unroll
    for (int ph = 0; ph < 2; ++ph) {
        int e2 = tid + ph * 256;
        float acc = bo[e2];
        for (int ee = 0; ee < 512; ++ee) acc += ctx[ee] * Wo[(size_t)ee * 512 + e2];
        pv[ph] = acc; psum += acc; psq += acc * acc;
    }
    for (int off = 32; off; off >>= 1) { psum += __shfl_xor(psum, off, 64); psq += __shfl_xor(psq, off, 64); }
    const int w = tid >> 6, lane = tid & 63;
    if (lane == 0) { red[w] = psum; red[4 + w] = psq; }
    __syncthreads();
    if (tid == 0) {
        float s = red[0] + red[1] + red[2] + red[3];
        float q2 = red[4] + red[5] + red[6] + red[7];
        float mu = s / 512.f;
        float var = q2 / 512.f - mu * mu;
        stats[0] = mu; stats[1] = 1.f / sqrtf(var + 1e-5f);
    }
    __syncthreads();
    #pragma unroll
    for (int ph = 0; ph < 2; ++ph) {
        int e2 = tid + ph * 256;
        y[(size_t)b * 512 + e2] = (pv[ph] - stats[0]) * stats[1] * g[e2] + lb[e2];
    }
}

// ---------------- head MLP layer 1: hid = relu(y@Wh1 + bh1)
__global__ __launch_bounds__(256) void h1_kernel(const float* __restrict__ y,
                                                 const float* __restrict__ Wh1,
                                                 const float* __restrict__ bh1,
                                                 float* __restrict__ hid) {
    __shared__ float ys[512];
    const int b = blockIdx.y, tid = threadIdx.x;
    ys[tid] = y[(size_t)b * 512 + tid];
    ys[tid + 256] = y[(size_t)b * 512 + tid + 256];
    __syncthreads();
    int j = blockIdx.x * 256 + tid;
    float acc = bh1[j];
    for (int dd = 0; dd < 512; ++dd) acc += ys[dd] * Wh1[(size_t)dd * 2048 + j];
    hid[(size_t)b * 2048 + j] = fmaxf(acc, 0.f);
}

// ---------------- head MLP layer 2: logits = hid@Wh2 + bh2
__global__ __launch_bounds__(256) void h2_kernel(const float* __restrict__ hid,
                                                 const float* __restrict__ Wh2,
                                                 const float* __restrict__ bh2,
                                                 float* __restrict__ out) {
    __shared__ float red[4];
    const int b = blockIdx.x, tid = threadIdx.x;
    float s = 0.f;
    for (int j = tid; j < 2048; j += 256) s += hid[(size_t)b * 2048 + j] * Wh2[j];
    for (int off = 32; off; off >>= 1) s += __shfl_xor(s, off, 64);
    const int w = tid >> 6, lane = tid & 63;
    if (lane == 0) red[w] = s;
    __syncthreads();
    if (tid == 0) out[b] = red[0] + red[1] + red[2] + red[3] + bh2[0];
}

extern "C" void kernel_launch(void* const* d_in, const int* in_sizes, int n_in,
                              void* d_out, int out_size, void* d_ws, size_t ws_size,
                              hipStream_t stream) {
    const int*   mut_idx = (const int*)d_in[0];
    const float* emb  = (const float*)d_in[2];
    const float* W1   = (const float*)d_in[3];
    const float* b1   = (const float*)d_in[4];
    const float* W2   = (const float*)d_in[5];
    const float* b2   = (const float*)d_in[6];
    const float* q    = (const float*)d_in[7];
    const float* Wq   = (const float*)d_in[8];
    const float* bq   = (const float*)d_in[9];
    const float* Wk   = (const float*)d_in[10];
    const float* bk   = (const float*)d_in[11];
    const float* Wv   = (const float*)d_in[12];
    const float* bv   = (const float*)d_in[13];
    const float* Wo   = (const float*)d_in[14];
    const float* bo   = (const float*)d_in[15];
    const float* ln_g = (const float*)d_in[16];
    const float* ln_b = (const float*)d_in[17];
    const float* Wh1  = (const float*)d_in[18];
    const float* bh1  = (const float*)d_in[19];
    const float* Wh2  = (const float*)d_in[20];
    const float* bh2  = (const float*)d_in[21];
    float* out = (float*)d_out;

    // fixed-footprint allocations (256B aligned)
    char* p = (char*)d_ws;
    auto alloc = [&](size_t bytes) {
        char* r = p; p += (bytes + 255) & ~(size_t)255; return r;
    };
    u16*  W1t  = (u16*)alloc((size_t)H_ * D_ * 2);      // [2048][512] bf16
    u16*  W2t  = (u16*)alloc((size_t)D_ * H_ * 2);      // [512][2048] bf16
    float* qp  = (float*)alloc(D_ * 4);
    float* wke = (float*)alloc((size_t)D_ * NH_ * 4);
    float* cke = (float*)alloc(NH_ * 4);
    float* scb  = (float*)alloc((size_t)B_ * NH_ * L_ * 4);        // scores/attn weights
    float* pbuf = (float*)alloc((size_t)B_ * 16 * NH_ * D_ * 4);   // wave partials of u
    float* ybuf = (float*)alloc((size_t)B_ * D_ * 4);
    float* hid  = (float*)alloc((size_t)B_ * H_ * 4);
    u16*  hbuf = (u16*)alloc((size_t)TOT * D_ * 2);     // full h, bf16

    size_t fixed = (size_t)(p - (char*)d_ws);
    // adaptive chunk: z (CH*1024 B) + C1 (CH*4096 B)
    int CH = 65536;
    while (CH > 1024 && fixed + (size_t)CH * 5120 + 8192 > ws_size) CH >>= 1;
    u16* z  = (u16*)alloc((size_t)CH * D_ * 2);
    u16* C1 = (u16*)alloc((size_t)CH * H_ * 2);

    // weight conversion / folding
    transpose_cvt<<<dim3(H_ / 32, D_ / 32), dim3(32, 8), 0, stream>>>(W1, W1t, D_, H_);
    transpose_cvt<<<dim3(D_ / 32, H_ / 32), dim3(32, 8), 0, stream>>>(W2, W2t, H_, D_);
    qp_kernel<<<2, 256, 0, stream>>>(q, Wq, bq, qp);
    wke_kernel<<<16, 256, 0, stream>>>(Wk, bk, qp, wke, cke);

    // phi MLP over token chunks  (m-tiles per chunk is CH/128 >= 8, divisible by 8)
    for (int c = 0; c * CH < TOT; ++c) {
        embed_kernel<<<CH / 4, 256, 0, stream>>>(mut_idx + c * CH, emb, z);
        gemm_bt<1, 4><<<dim3((CH / 128) * 16), 256, 0, stream>>>(z, W1t, b1, C1, H_, D_);
        gemm_bt<0, 2><<<dim3((CH / 128) * 4), 256, 0, stream>>>(C1, W2t, b2,
                                                                hbuf + (size_t)c * CH * D_, D_, H_);
    }

    // attention pool + head
    score_kernel<<<dim3(16, B_), 256, 0, stream>>>(hbuf, wke, cke, scb);
    softmax_kernel<<<B_ * NH_, 256, 0, stream>>>(scb);
    wsum_kernel<<<dim3(4, B_), 256, 0, stream>>>(hbuf, scb, pbuf);
    pool_kernel<<<B_, 256, 0, stream>>>(pbuf, Wv, bv, Wo, bo, ln_g, ln_b, ybuf);
    h1_kernel<<<dim3(H_ / 256, B_), 256, 0, stream>>>(ybuf, Wh1, bh1, hid);
    h2_kernel<<<B_, 256, 0, stream>>>(hid, Wh2, bh2, out);
}

// Round 5
// 844.786 us; speedup vs baseline: 1.1246x; 1.1246x over previous
//
#include <hip/hip_runtime.h>
#include <hip/hip_bf16.h>

using u16 = unsigned short;
typedef __bf16 bf16x8_t __attribute__((ext_vector_type(8)));
typedef float    f32x4  __attribute__((ext_vector_type(4)));
typedef unsigned short u16x8 __attribute__((ext_vector_type(8)));

#define B_  64
#define L_  1024
#define TOT 65536
#define D_  512
#define H_  2048
#define NH_ 8

__device__ __forceinline__ float b2f(u16 x) {
    union { unsigned int i; float f; } v; v.i = ((unsigned int)x) << 16; return v.f;
}
__device__ __forceinline__ u16 f2b(float f) {
    union { float f; unsigned int i; } v; v.f = f;
    unsigned int i = v.i;
    unsigned int r = i + 0x7FFFu + ((i >> 16) & 1u);   // RNE
    return (u16)(r >> 16);
}

// ---------------- transpose + fp32->bf16 convert:  in[R][C] f32 -> out[C][R] bf16
__global__ __launch_bounds__(256) void transpose_cvt(const float* __restrict__ in,
                                                     u16* __restrict__ out, int R, int C) {
    __shared__ float tile[32][33];
    int c0 = blockIdx.x * 32, r0 = blockIdx.y * 32;
    int tx = threadIdx.x, ty = threadIdx.y;
    #pragma unroll
    for (int i = 0; i < 4; ++i)
        tile[ty + 8 * i][tx] = in[(size_t)(r0 + ty + 8 * i) * C + c0 + tx];
    __syncthreads();
    #pragma unroll
    for (int i = 0; i < 4; ++i)
        out[(size_t)(c0 + ty + 8 * i) * R + r0 + tx] = f2b(tile[tx][ty + 8 * i]);
}

// ---------------- qp = q @ Wq + bq   (512 outputs, 2 blocks)
__global__ __launch_bounds__(256) void qp_kernel(const float* __restrict__ q,
                                                 const float* __restrict__ Wq,
                                                 const float* __restrict__ bq,
                                                 float* __restrict__ qp) {
    __shared__ float qs[512];
    int tid = threadIdx.x;
    qs[tid] = q[tid]; qs[tid + 256] = q[tid + 256];
    __syncthreads();
    int j = blockIdx.x * 256 + tid;
    float acc = bq[j];
    for (int d = 0; d < 512; ++d) acc += qs[d] * Wq[(size_t)d * 512 + j];
    qp[j] = acc;
}

// ---------------- wke[d][h] = 0.125 * sum_j Wk[d, h*64+j]*qp[h*64+j];  cke[h] from bk
__global__ __launch_bounds__(256) void wke_kernel(const float* __restrict__ Wk,
                                                  const float* __restrict__ bk,
                                                  const float* __restrict__ qp,
                                                  float* __restrict__ wke,
                                                  float* __restrict__ cke) {
    __shared__ float qs[512];
    int tid = threadIdx.x;
    qs[tid] = qp[tid]; qs[tid + 256] = qp[tid + 256];
    __syncthreads();
    int d = blockIdx.x * 32 + (tid >> 3);
    int h = tid & 7;
    float s = 0.f;
    for (int j = 0; j < 64; ++j) s += Wk[(size_t)d * 512 + h * 64 + j] * qs[h * 64 + j];
    wke[d * 8 + h] = 0.125f * s;
    if (blockIdx.x == 0 && tid < 8) {
        float c = 0.f;
        for (int j = 0; j < 64; ++j) c += bk[tid * 64 + j] * qs[tid * 64 + j];
        cke[tid] = 0.125f * c;
    }
}

// ---------------- gather emb rows -> bf16 z chunk
__global__ __launch_bounds__(256) void embed_kernel(const int* __restrict__ idx,
                                                    const float* __restrict__ emb,
                                                    u16* __restrict__ z) {
    int u = blockIdx.x * 256 + threadIdx.x;   // one unit = 8 elements
    int t = u >> 6;                            // 64 units per 512-wide row
    int d0 = (u & 63) * 8;
    int row = idx[t];
    const float4* src = (const float4*)(emb + (size_t)row * 512 + d0);
    float4 a = src[0], b = src[1];
    u16x8 o;
    o[0] = f2b(a.x); o[1] = f2b(a.y); o[2] = f2b(a.z); o[3] = f2b(a.w);
    o[4] = f2b(b.x); o[5] = f2b(b.y); o[6] = f2b(b.z); o[7] = f2b(b.w);
    *(u16x8*)(z + (size_t)t * 512 + d0) = o;
}

// ---------------- bf16 GEMM 128x128, BK=64 (4 waves) — used for gemm2
template <int RELU, int LNT>
__global__ __launch_bounds__(256) void gemm_bt(const u16* __restrict__ A,
                                               const u16* __restrict__ Bt,
                                               const float* __restrict__ bias,
                                               u16* __restrict__ C,
                                               int N, int K) {
    __shared__ __align__(16) u16 As[128 * 64];
    __shared__ __align__(16) u16 Bs[128 * 64];
    const int tid = threadIdx.x;
    const int id = blockIdx.x;
    const int xcd = id & 7, s = id >> 3;
    const int n_idx = s & ((1 << LNT) - 1);
    const int m_idx = xcd + 8 * (s >> LNT);
    const int m0 = m_idx * 128, n0 = n_idx * 128;
    const int lane = tid & 63, quad = lane >> 4, l15 = lane & 15;
    const int wave = tid >> 6, wm = wave >> 1, wn = wave & 1;

    f32x4 acc[4][4] = {};

    const int nK = K >> 6;
    for (int kt = 0; kt < nK; ++kt) {
        __syncthreads();
        const int kb = kt * 64;
        #pragma unroll
        for (int r = 0; r < 4; ++r) {
            int u = tid + r * 256;
            int row = u >> 3;
            int cg = (u & 7) ^ (row & 7);    // global colgroup stored in this LDS slot
            const u16* ga = A + (size_t)(m0 + row) * K + kb + cg * 8;
            __builtin_amdgcn_global_load_lds((const __attribute__((address_space(1))) void*)ga,
                                             (__attribute__((address_space(3))) void*)(&As[u * 8]),
                                             16, 0, 0);
            const u16* gb = Bt + (size_t)(n0 + row) * K + kb + cg * 8;
            __builtin_amdgcn_global_load_lds((const __attribute__((address_space(1))) void*)gb,
                                             (__attribute__((address_space(3))) void*)(&Bs[u * 8]),
                                             16, 0, 0);
        }
        __syncthreads();
        #pragma unroll
        for (int ks = 0; ks < 2; ++ks) {
            bf16x8_t af[4], bfr[4];
            #pragma unroll
            for (int mt = 0; mt < 4; ++mt) {
                int row = wm * 64 + mt * 16 + l15;
                int g = (ks * 4 + quad) ^ (row & 7);
                af[mt] = *(const bf16x8_t*)&As[row * 64 + g * 8];
            }
            #pragma unroll
            for (int nt = 0; nt < 4; ++nt) {
                int row = wn * 64 + nt * 16 + l15;
                int g = (ks * 4 + quad) ^ (row & 7);
                bfr[nt] = *(const bf16x8_t*)&Bs[row * 64 + g * 8];
            }
            #pragma unroll
            for (int mt = 0; mt < 4; ++mt)
                #pragma unroll
                for (int nt = 0; nt < 4; ++nt)
                    acc[mt][nt] = __builtin_amdgcn_mfma_f32_16x16x32_bf16(af[mt], bfr[nt],
                                                                          acc[mt][nt], 0, 0, 0);
        }
    }

    float bvv[4];
    #pragma unroll
    for (int nt = 0; nt < 4; ++nt) bvv[nt] = bias[n0 + wn * 64 + nt * 16 + l15];
    #pragma unroll
    for (int mt = 0; mt < 4; ++mt)
        #pragma unroll
        for (int nt = 0; nt < 4; ++nt)
            #pragma unroll
            for (int r = 0; r < 4; ++r) {
                int row = m0 + wm * 64 + mt * 16 + quad * 4 + r;
                int col = n0 + wn * 64 + nt * 16 + l15;
                float v = acc[mt][nt][r] + bvv[nt];
                if (RELU) v = fmaxf(v, 0.f);
                C[(size_t)row * N + col] = f2b(v);
            }
}

// ---------------- bf16 GEMM 256x128, BK=64, 8 waves — used for gemm1.
// 2x MFMA per barrier-drain per CU vs 128-tile; 6 staging loads/thread/iter.
template <int RELU, int LNT>
__global__ __launch_bounds__(512) void gemm_bt256(const u16* __restrict__ A,
                                                  const u16* __restrict__ Bt,
                                                  const float* __restrict__ bias,
                                                  u16* __restrict__ C,
                                                  int N, int K) {
    __shared__ __align__(16) u16 As[256 * 64];
    __shared__ __align__(16) u16 Bs[128 * 64];
    const int tid = threadIdx.x;
    const int id = blockIdx.x;
    const int xcd = id & 7, s = id >> 3;
    const int n_idx = s & ((1 << LNT) - 1);
    const int m_idx = xcd + 8 * (s >> LNT);
    const int m0 = m_idx * 256, n0 = n_idx * 128;
    const int lane = tid & 63, quad = lane >> 4, l15 = lane & 15;
    const int wave = tid >> 6, wm = wave >> 1, wn = wave & 1;   // wm 0..3, wn 0..1

    f32x4 acc[4][4] = {};

    const int nK = K >> 6;
    for (int kt = 0; kt < nK; ++kt) {
        __syncthreads();
        const int kb = kt * 64;
        #pragma unroll
        for (int r = 0; r < 4; ++r) {           // As: 256 rows x 8 groups = 2048 slots
            int u = tid + r * 512;
            int row = u >> 3;
            int cg = (u & 7) ^ (row & 7);
            const u16* ga = A + (size_t)(m0 + row) * K + kb + cg * 8;
            __builtin_amdgcn_global_load_lds((const __attribute__((address_space(1))) void*)ga,
                                             (__attribute__((address_space(3))) void*)(&As[u * 8]),
                                             16, 0, 0);
        }
        #pragma unroll
        for (int r = 0; r < 2; ++r) {           // Bs: 128 rows x 8 groups = 1024 slots
            int u = tid + r * 512;
            int row = u >> 3;
            int cg = (u & 7) ^ (row & 7);
            const u16* gb = Bt + (size_t)(n0 + row) * K + kb + cg * 8;
            __builtin_amdgcn_global_load_lds((const __attribute__((address_space(1))) void*)gb,
                                             (__attribute__((address_space(3))) void*)(&Bs[u * 8]),
                                             16, 0, 0);
        }
        __syncthreads();
        #pragma unroll
        for (int ks = 0; ks < 2; ++ks) {
            bf16x8_t af[4], bfr[4];
            #pragma unroll
            for (int mt = 0; mt < 4; ++mt) {
                int row = wm * 64 + mt * 16 + l15;
                int g = (ks * 4 + quad) ^ (row & 7);
                af[mt] = *(const bf16x8_t*)&As[row * 64 + g * 8];
            }
            #pragma unroll
            for (int nt = 0; nt < 4; ++nt) {
                int row = wn * 64 + nt * 16 + l15;
                int g = (ks * 4 + quad) ^ (row & 7);
                bfr[nt] = *(const bf16x8_t*)&Bs[row * 64 + g * 8];
            }
            #pragma unroll
            for (int mt = 0; mt < 4; ++mt)
                #pragma unroll
                for (int nt = 0; nt < 4; ++nt)
                    acc[mt][nt] = __builtin_amdgcn_mfma_f32_16x16x32_bf16(af[mt], bfr[nt],
                                                                          acc[mt][nt], 0, 0, 0);
        }
    }

    float bvv[4];
    #pragma unroll
    for (int nt = 0; nt < 4; ++nt) bvv[nt] = bias[n0 + wn * 64 + nt * 16 + l15];
    #pragma unroll
    for (int mt = 0; mt < 4; ++mt)
        #pragma unroll
        for (int nt = 0; nt < 4; ++nt)
            #pragma unroll
            for (int r = 0; r < 4; ++r) {
                int row = m0 + wm * 64 + mt * 16 + quad * 4 + r;
                int col = n0 + wn * 64 + nt * 16 + l15;
                float v = acc[mt][nt][r] + bvv[nt];
                if (RELU) v = fmaxf(v, 0.f);
                C[(size_t)row * N + col] = f2b(v);
            }
}

// ---------------- scores[b][h][l] = h[b,l,:] . wke[:,h] + cke[h]
__global__ __launch_bounds__(256) void score_kernel(const u16* __restrict__ h,
                                                    const float* __restrict__ wke,
                                                    const float* __restrict__ cke,
                                                    float* __restrict__ scb) {
    const int b = blockIdx.y, lc = blockIdx.x, tid = threadIdx.x;
    const int w = tid >> 6, lane = tid & 63;

    float wkr[8][8];
    #pragma unroll
    for (int j = 0; j < 8; ++j)
        #pragma unroll
        for (int hh = 0; hh < 8; ++hh) wkr[j][hh] = wke[(lane * 8 + j) * 8 + hh];
    float cr[8];
    #pragma unroll
    for (int hh = 0; hh < 8; ++hh) cr[hh] = cke[hh];

    const u16* hb = h + (size_t)b * 1024 * 512;

    #pragma unroll 2
    for (int i = 0; i < 16; ++i) {
        int l = lc * 64 + w * 16 + i;
        u16x8 hv = *(const u16x8*)(hb + (size_t)l * 512 + lane * 8);
        float s[8] = {0, 0, 0, 0, 0, 0, 0, 0};
        #pragma unroll
        for (int j = 0; j < 8; ++j) {
            float hf = b2f(hv[j]);
            #pragma unroll
            for (int hh = 0; hh < 8; ++hh) s[hh] += hf * wkr[j][hh];
        }
        #pragma unroll
        for (int hh = 0; hh < 8; ++hh) {
            float v = s[hh];
            for (int off = 32; off; off >>= 1) v += __shfl_xor(v, off, 64);
            if (lane == 0) scb[((size_t)b * 8 + hh) * 1024 + l] = v + cr[hh];
        }
    }
}

// ---------------- softmax over l for each (b,h); in-place on scb. grid 512.
__global__ __launch_bounds__(256) void softmax_kernel(float* __restrict__ scb) {
    __shared__ float red[8];
    const int bh = blockIdx.x, tid = threadIdx.x;
    const int w = tid >> 6, lane = tid & 63;
    float* p = scb + (size_t)bh * 1024;
    float4 v = ((float4*)p)[tid];
    float m = fmaxf(fmaxf(v.x, v.y), fmaxf(v.z, v.w));
    for (int off = 32; off; off >>= 1) m = fmaxf(m, __shfl_xor(m, off, 64));
    if (lane == 0) red[w] = m;
    __syncthreads();
    m = fmaxf(fmaxf(red[0], red[1]), fmaxf(red[2], red[3]));
    float4 e;
    e.x = __expf(v.x - m); e.y = __expf(v.y - m);
    e.z = __expf(v.z - m); e.w = __expf(v.w - m);
    float s = e.x + e.y + e.z + e.w;
    for (int off = 32; off; off >>= 1) s += __shfl_xor(s, off, 64);
    __syncthreads();
    if (lane == 0) red[4 + w] = s;
    __syncthreads();
    float inv = 1.f / (red[4] + red[5] + red[6] + red[7]);
    e.x *= inv; e.y *= inv; e.z *= inv; e.w *= inv;
    ((float4*)p)[tid] = e;
}

// ---------------- wave partials of u
__global__ __launch_bounds__(256) void wsum_kernel(const u16* __restrict__ h,
                                                   const float* __restrict__ scb,
                                                   float* __restrict__ pbuf) {
    __shared__ float as[8][256];
    const int b = blockIdx.y, c = blockIdx.x, tid = threadIdx.x;
    const int w = tid >> 6, lane = tid & 63;
    for (int i = tid; i < 2048; i += 256) {
        int hh = i >> 8, l = i & 255;
        as[hh][l] = scb[((size_t)b * 8 + hh) * 1024 + c * 256 + l];
    }
    __syncthreads();
    const u16* hb = h + ((size_t)b * 1024 + c * 256 + w * 64) * 512 + lane * 8;
    float acc[8][8] = {};
    for (int i = 0; i < 64; ++i) {
        u16x8 hv = *(const u16x8*)(hb + (size_t)i * 512);
        int l = w * 64 + i;
        float av[8];
        #pragma unroll
        for (int hh = 0; hh < 8; ++hh) av[hh] = as[hh][l];
        #pragma unroll
        for (int j = 0; j < 8; ++j) {
            float hf = b2f(hv[j]);
            #pragma unroll
            for (int hh = 0; hh < 8; ++hh) acc[hh][j] += av[hh] * hf;
        }
    }
    float* pw = pbuf + ((size_t)b * 16 + c * 4 + w) * 4096;
    #pragma unroll
    for (int hh = 0; hh < 8; ++hh) {
        float4 lo, hi;
        lo.x = acc[hh][0]; lo.y = acc[hh][1]; lo.z = acc[hh][2]; lo.w = acc[hh][3];
        hi.x = acc[hh][4]; hi.y = acc[hh][5]; hi.z = acc[hh][6]; hi.w = acc[hh][7];
        *(float4*)(pw + hh * 512 + lane * 8) = lo;
        *(float4*)(pw + hh * 512 + lane * 8 + 4) = hi;
    }
}

// ---------------- per-set: fold partials; ctx = u@Wv + bv; pooled = ctx@Wo + bo; LN -> y
__global__ __launch_bounds__(256) void pool_kernel(const float* __restrict__ pbuf,
                                                   const float* __restrict__ Wv,
                                                   const float* __restrict__ bv,
                                                   const float* __restrict__ Wo,
                                                   const float* __restrict__ bo,
                                                   const float* __restrict__ g,
                                                   const float* __restrict__ lb,
                                                   float* __restrict__ y) {
    __shared__ float us[8 * 512];
    __shared__ float ctx[512];
    __shared__ float red[8];
    __shared__ float stats[2];
    const int b = blockIdx.x, tid = threadIdx.x;
    for (int i = tid; i < 4096; i += 256) {
        float s = 0.f;
        #pragma unroll
        for (int c = 0; c < 16; ++c) s += pbuf[((size_t)b * 16 + c) * 4096 + i];
        us[i] = s;
    }
    __syncthreads();
    #pragma unroll
    for (int ph = 0; ph < 2; ++ph) {
        int e = tid + ph * 256;
        int hh = e >> 6;
        float acc = bv[e];
        for (int dd = 0; dd < 512; ++dd) acc += us[hh * 512 + dd] * Wv[(size_t)dd * 512 + e];
        ctx[e] = acc;
    }
    __syncthreads();
    float pv[2]; float psum = 0.f, psq = 0.f;
    #pragma unroll
    for (int ph = 0; ph < 2; ++ph) {
        int e2 = tid + ph * 256;
        float acc = bo[e2];
        for (int ee = 0; ee < 512; ++ee) acc += ctx[ee] * Wo[(size_t)ee * 512 + e2];
        pv[ph] = acc; psum += acc; psq += acc * acc;
    }
    for (int off = 32; off; off >>= 1) { psum += __shfl_xor(psum, off, 64); psq += __shfl_xor(psq, off, 64); }
    const int w = tid >> 6, lane = tid & 63;
    if (lane == 0) { red[w] = psum; red[4 + w] = psq; }
    __syncthreads();
    if (tid == 0) {
        float s = red[0] + red[1] + red[2] + red[3];
        float q2 = red[4] + red[5] + red[6] + red[7];
        float mu = s / 512.f;
        float var = q2 / 512.f - mu * mu;
        stats[0] = mu; stats[1] = 1.f / sqrtf(var + 1e-5f);
    }
    __syncthreads();
    #pragma unroll
    for (int ph = 0; ph < 2; ++ph) {
        int e2 = tid + ph * 256;
        y[(size_t)b * 512 + e2] = (pv[ph] - stats[0]) * stats[1] * g[e2] + lb[e2];
    }
}

// ---------------- head MLP layer 1: hid = relu(y@Wh1 + bh1)
__global__ __launch_bounds__(256) void h1_kernel(const float* __restrict__ y,
                                                 const float* __restrict__ Wh1,
                                                 const float* __restrict__ bh1,
                                                 float* __restrict__ hid) {
    __shared__ float ys[512];
    const int b = blockIdx.y, tid = threadIdx.x;
    ys[tid] = y[(size_t)b * 512 + tid];
    ys[tid + 256] = y[(size_t)b * 512 + tid + 256];
    __syncthreads();
    int j = blockIdx.x * 256 + tid;
    float acc = bh1[j];
    for (int dd = 0; dd < 512; ++dd) acc += ys[dd] * Wh1[(size_t)dd * 2048 + j];
    hid[(size_t)b * 2048 + j] = fmaxf(acc, 0.f);
}

// ---------------- head MLP layer 2: logits = hid@Wh2 + bh2
__global__ __launch_bounds__(256) void h2_kernel(const float* __restrict__ hid,
                                                 const float* __restrict__ Wh2,
                                                 const float* __restrict__ bh2,
                                                 float* __restrict__ out) {
    __shared__ float red[4];
    const int b = blockIdx.x, tid = threadIdx.x;
    float s = 0.f;
    for (int j = tid; j < 2048; j += 256) s += hid[(size_t)b * 2048 + j] * Wh2[j];
    for (int off = 32; off; off >>= 1) s += __shfl_xor(s, off, 64);
    const int w = tid >> 6, lane = tid & 63;
    if (lane == 0) red[w] = s;
    __syncthreads();
    if (tid == 0) out[b] = red[0] + red[1] + red[2] + red[3] + bh2[0];
}

extern "C" void kernel_launch(void* const* d_in, const int* in_sizes, int n_in,
                              void* d_out, int out_size, void* d_ws, size_t ws_size,
                              hipStream_t stream) {
    const int*   mut_idx = (const int*)d_in[0];
    const float* emb  = (const float*)d_in[2];
    const float* W1   = (const float*)d_in[3];
    const float* b1   = (const float*)d_in[4];
    const float* W2   = (const float*)d_in[5];
    const float* b2   = (const float*)d_in[6];
    const float* q    = (const float*)d_in[7];
    const float* Wq   = (const float*)d_in[8];
    const float* bq   = (const float*)d_in[9];
    const float* Wk   = (const float*)d_in[10];
    const float* bk   = (const float*)d_in[11];
    const float* Wv   = (const float*)d_in[12];
    const float* bv   = (const float*)d_in[13];
    const float* Wo   = (const float*)d_in[14];
    const float* bo   = (const float*)d_in[15];
    const float* ln_g = (const float*)d_in[16];
    const float* ln_b = (const float*)d_in[17];
    const float* Wh1  = (const float*)d_in[18];
    const float* bh1  = (const float*)d_in[19];
    const float* Wh2  = (const float*)d_in[20];
    const float* bh2  = (const float*)d_in[21];
    float* out = (float*)d_out;

    // fixed-footprint allocations (256B aligned)
    char* p = (char*)d_ws;
    auto alloc = [&](size_t bytes) {
        char* r = p; p += (bytes + 255) & ~(size_t)255; return r;
    };
    u16*  W1t  = (u16*)alloc((size_t)H_ * D_ * 2);      // [2048][512] bf16
    u16*  W2t  = (u16*)alloc((size_t)D_ * H_ * 2);      // [512][2048] bf16
    float* qp  = (float*)alloc(D_ * 4);
    float* wke = (float*)alloc((size_t)D_ * NH_ * 4);
    float* cke = (float*)alloc(NH_ * 4);
    float* scb  = (float*)alloc((size_t)B_ * NH_ * L_ * 4);        // scores/attn weights
    float* pbuf = (float*)alloc((size_t)B_ * 16 * NH_ * D_ * 4);   // wave partials of u
    float* ybuf = (float*)alloc((size_t)B_ * D_ * 4);
    float* hid  = (float*)alloc((size_t)B_ * H_ * 4);
    u16*  hbuf = (u16*)alloc((size_t)TOT * D_ * 2);     // full h, bf16

    size_t fixed = (size_t)(p - (char*)d_ws);
    // chunk CH=16384: z (16 MB) + C1 (67 MB) stay L3-resident across the
    // gemm1->gemm2 producer/consumer pair -> staging drain is L3-hit not HBM-miss.
    int CH = 16384;
    while (CH > 2048 && fixed + (size_t)CH * 5120 + 8192 > ws_size) CH >>= 1;
    u16* z  = (u16*)alloc((size_t)CH * D_ * 2);
    u16* C1 = (u16*)alloc((size_t)CH * H_ * 2);

    // weight conversion / folding
    transpose_cvt<<<dim3(H_ / 32, D_ / 32), dim3(32, 8), 0, stream>>>(W1, W1t, D_, H_);
    transpose_cvt<<<dim3(D_ / 32, H_ / 32), dim3(32, 8), 0, stream>>>(W2, W2t, H_, D_);
    qp_kernel<<<2, 256, 0, stream>>>(q, Wq, bq, qp);
    wke_kernel<<<16, 256, 0, stream>>>(Wk, bk, qp, wke, cke);

    // phi MLP over token chunks
    for (int c = 0; c * CH < TOT; ++c) {
        embed_kernel<<<CH / 4, 256, 0, stream>>>(mut_idx + c * CH, emb, z);
        gemm_bt256<1, 4><<<dim3((CH / 256) * 16), 512, 0, stream>>>(z, W1t, b1, C1, H_, D_);
        gemm_bt<0, 2><<<dim3((CH / 128) * 4), 256, 0, stream>>>(C1, W2t, b2,
                                                                hbuf + (size_t)c * CH * D_, D_, H_);
    }

    // attention pool + head
    score_kernel<<<dim3(16, B_), 256, 0, stream>>>(hbuf, wke, cke, scb);
    softmax_kernel<<<B_ * NH_, 256, 0, stream>>>(scb);
    wsum_kernel<<<dim3(4, B_), 256, 0, stream>>>(hbuf, scb, pbuf);
    pool_kernel<<<B_, 256, 0, stream>>>(pbuf, Wv, bv, Wo, bo, ln_g, ln_b, ybuf);
    h1_kernel<<<dim3(H_ / 256, B_), 256, 0, stream>>>(ybuf, Wh1, bh1, hid);
    h2_kernel<<<B_, 256, 0, stream>>>(hid, Wh2, bh2, out);
}

// Round 6
// 833.451 us; speedup vs baseline: 1.1399x; 1.0136x over previous
//
#include <hip/hip_runtime.h>
#include <hip/hip_bf16.h>

using u16 = unsigned short;
typedef __bf16 bf16x8_t __attribute__((ext_vector_type(8)));
typedef float    f32x4  __attribute__((ext_vector_type(4)));
typedef unsigned short u16x8 __attribute__((ext_vector_type(8)));

#define B_  64
#define L_  1024
#define TOT 65536
#define D_  512
#define H_  2048
#define NH_ 8
#define NC_ 8   // l-chunks for wsum partials

__device__ __forceinline__ float b2f(u16 x) {
    union { unsigned int i; float f; } v; v.i = ((unsigned int)x) << 16; return v.f;
}
__device__ __forceinline__ u16 f2b(float f) {
    union { float f; unsigned int i; } v; v.f = f;
    unsigned int i = v.i;
    unsigned int r = i + 0x7FFFu + ((i >> 16) & 1u);   // RNE
    return (u16)(r >> 16);
}

// ---------------- transpose + fp32->bf16 convert:  in[R][C] f32 -> out[C][R] bf16
__global__ __launch_bounds__(256) void transpose_cvt(const float* __restrict__ in,
                                                     u16* __restrict__ out, int R, int C) {
    __shared__ float tile[32][33];
    int c0 = blockIdx.x * 32, r0 = blockIdx.y * 32;
    int tx = threadIdx.x, ty = threadIdx.y;
    #pragma unroll
    for (int i = 0; i < 4; ++i)
        tile[ty + 8 * i][tx] = in[(size_t)(r0 + ty + 8 * i) * C + c0 + tx];
    __syncthreads();
    #pragma unroll
    for (int i = 0; i < 4; ++i)
        out[(size_t)(c0 + ty + 8 * i) * R + r0 + tx] = f2b(tile[tx][ty + 8 * i]);
}

// ---------------- qp = q @ Wq + bq
__global__ __launch_bounds__(256) void qp_kernel(const float* __restrict__ q,
                                                 const float* __restrict__ Wq,
                                                 const float* __restrict__ bq,
                                                 float* __restrict__ qp) {
    __shared__ float qs[512];
    int tid = threadIdx.x;
    qs[tid] = q[tid]; qs[tid + 256] = q[tid + 256];
    __syncthreads();
    int j = blockIdx.x * 256 + tid;
    float acc = bq[j];
    for (int d = 0; d < 512; ++d) acc += qs[d] * Wq[(size_t)d * 512 + j];
    qp[j] = acc;
}

// ---------------- wke[d][h] = 0.125*sum_j Wk[d,h*64+j]*qp[h*64+j];  cke[h] from bk
__global__ __launch_bounds__(256) void wke_kernel(const float* __restrict__ Wk,
                                                  const float* __restrict__ bk,
                                                  const float* __restrict__ qp,
                                                  float* __restrict__ wke,
                                                  float* __restrict__ cke) {
    __shared__ float qs[512];
    int tid = threadIdx.x;
    qs[tid] = qp[tid]; qs[tid + 256] = qp[tid + 256];
    __syncthreads();
    int d = blockIdx.x * 32 + (tid >> 3);
    int h = tid & 7;
    float s = 0.f;
    for (int j = 0; j < 64; ++j) s += Wk[(size_t)d * 512 + h * 64 + j] * qs[h * 64 + j];
    wke[d * 8 + h] = 0.125f * s;
    if (blockIdx.x == 0 && tid < 8) {
        float c = 0.f;
        for (int j = 0; j < 64; ++j) c += bk[tid * 64 + j] * qs[tid * 64 + j];
        cke[tid] = 0.125f * c;
    }
}

// ---------------- wv2t[h][k] = bf16( sum_d W2[k][d]*wke[d][h] ), rows 8..15 zero.
// ck2[h] = sum_d b2[d]*wke[d][h] + cke[h]
__global__ __launch_bounds__(256) void wv2_kernel(const float* __restrict__ W2,
                                                  const float* __restrict__ wke,
                                                  const float* __restrict__ cke,
                                                  const float* __restrict__ b2,
                                                  u16* __restrict__ wv2t,
                                                  float* __restrict__ ck2) {
    __shared__ float wk[512 * 8];
    int tid = threadIdx.x;
    for (int i = tid; i < 4096; i += 256) wk[i] = wke[i];
    __syncthreads();
    int k = blockIdx.x * 32 + (tid >> 3);
    int h = tid & 7;
    float s = 0.f;
    const float* row = W2 + (size_t)k * 512;
    for (int d = 0; d < 512; ++d) s += row[d] * wk[d * 8 + h];
    wv2t[(size_t)h * 2048 + k] = f2b(s);
    wv2t[(size_t)(h + 8) * 2048 + k] = 0;
    if (blockIdx.x == 0 && tid < 8) {
        float c = 0.f;
        for (int d = 0; d < 512; ++d) c += b2[d] * wk[d * 8 + tid];
        ck2[tid] = c + cke[tid];
    }
}

// ---------------- cvv[e] = sum_d b2[d]*Wv[d][e] + bv[e]
__global__ __launch_bounds__(256) void cvv_kernel(const float* __restrict__ Wv,
                                                  const float* __restrict__ b2,
                                                  const float* __restrict__ bv,
                                                  float* __restrict__ cvv) {
    int e = blockIdx.x * 256 + threadIdx.x;
    float s = bv[e];
    for (int d = 0; d < 512; ++d) s += b2[d] * Wv[(size_t)d * 512 + e];
    cvv[e] = s;
}

// ---------------- WW[2048][512] = W2[2048][512] @ Wv[512][512]  (fp32 tiled)
__global__ __launch_bounds__(256) void ww_kernel(const float* __restrict__ W2,
                                                 const float* __restrict__ Wv,
                                                 float* __restrict__ WW) {
    __shared__ float As[64][65];
    __shared__ float Bs[64][65];
    const int m0 = blockIdx.y * 64, n0 = blockIdx.x * 64;
    const int tid = threadIdx.x;
    const int tx = tid & 15, ty = tid >> 4;
    float acc[4][4] = {};
    for (int k0 = 0; k0 < 512; k0 += 64) {
        for (int i = tid; i < 4096; i += 256) {
            int r = i >> 6, c = i & 63;
            As[r][c] = W2[(size_t)(m0 + r) * 512 + k0 + c];
            Bs[r][c] = Wv[(size_t)(k0 + r) * 512 + n0 + c];
        }
        __syncthreads();
        for (int kk = 0; kk < 64; ++kk) {
            float a[4], b[4];
            #pragma unroll
            for (int i = 0; i < 4; ++i) a[i] = As[ty * 4 + i][kk];
            #pragma unroll
            for (int j = 0; j < 4; ++j) b[j] = Bs[kk][tx * 4 + j];
            #pragma unroll
            for (int i = 0; i < 4; ++i)
                #pragma unroll
                for (int j = 0; j < 4; ++j) acc[i][j] += a[i] * b[j];
        }
        __syncthreads();
    }
    #pragma unroll
    for (int i = 0; i < 4; ++i)
        #pragma unroll
        for (int j = 0; j < 4; ++j)
            WW[(size_t)(m0 + ty * 4 + i) * 512 + n0 + tx * 4 + j] = acc[i][j];
}

// ---------------- gather emb rows -> bf16 z
__global__ __launch_bounds__(256) void embed_kernel(const int* __restrict__ idx,
                                                    const float* __restrict__ emb,
                                                    u16* __restrict__ z) {
    int u = blockIdx.x * 256 + threadIdx.x;   // one unit = 8 elements
    int t = u >> 6;
    int d0 = (u & 63) * 8;
    int row = idx[t];
    const float4* src = (const float4*)(emb + (size_t)row * 512 + d0);
    float4 a = src[0], b = src[1];
    u16x8 o;
    o[0] = f2b(a.x); o[1] = f2b(a.y); o[2] = f2b(a.z); o[3] = f2b(a.w);
    o[4] = f2b(b.x); o[5] = f2b(b.y); o[6] = f2b(b.z); o[7] = f2b(b.w);
    *(u16x8*)(z + (size_t)t * 512 + d0) = o;
}

// ---------------- bf16 GEMM 256x128, BK=64, 8 waves: C = relu(A@Bt^T + bias)
template <int RELU, int LNT>
__global__ __launch_bounds__(512) void gemm_bt256(const u16* __restrict__ A,
                                                  const u16* __restrict__ Bt,
                                                  const float* __restrict__ bias,
                                                  u16* __restrict__ C,
                                                  int N, int K) {
    __shared__ __align__(16) u16 As[256 * 64];
    __shared__ __align__(16) u16 Bs[128 * 64];
    const int tid = threadIdx.x;
    const int id = blockIdx.x;
    const int xcd = id & 7, s = id >> 3;
    const int n_idx = s & ((1 << LNT) - 1);
    const int m_idx = xcd + 8 * (s >> LNT);
    const int m0 = m_idx * 256, n0 = n_idx * 128;
    const int lane = tid & 63, quad = lane >> 4, l15 = lane & 15;
    const int wave = tid >> 6, wm = wave >> 1, wn = wave & 1;

    f32x4 acc[4][4] = {};

    const int nK = K >> 6;
    for (int kt = 0; kt < nK; ++kt) {
        __syncthreads();
        const int kb = kt * 64;
        #pragma unroll
        for (int r = 0; r < 4; ++r) {
            int u = tid + r * 512;
            int row = u >> 3;
            int cg = (u & 7) ^ (row & 7);
            const u16* ga = A + (size_t)(m0 + row) * K + kb + cg * 8;
            __builtin_amdgcn_global_load_lds((const __attribute__((address_space(1))) void*)ga,
                                             (__attribute__((address_space(3))) void*)(&As[u * 8]),
                                             16, 0, 0);
        }
        #pragma unroll
        for (int r = 0; r < 2; ++r) {
            int u = tid + r * 512;
            int row = u >> 3;
            int cg = (u & 7) ^ (row & 7);
            const u16* gb = Bt + (size_t)(n0 + row) * K + kb + cg * 8;
            __builtin_amdgcn_global_load_lds((const __attribute__((address_space(1))) void*)gb,
                                             (__attribute__((address_space(3))) void*)(&Bs[u * 8]),
                                             16, 0, 0);
        }
        __syncthreads();
        #pragma unroll
        for (int ks = 0; ks < 2; ++ks) {
            bf16x8_t af[4], bfr[4];
            #pragma unroll
            for (int mt = 0; mt < 4; ++mt) {
                int row = wm * 64 + mt * 16 + l15;
                int g = (ks * 4 + quad) ^ (row & 7);
                af[mt] = *(const bf16x8_t*)&As[row * 64 + g * 8];
            }
            #pragma unroll
            for (int nt = 0; nt < 4; ++nt) {
                int row = wn * 64 + nt * 16 + l15;
                int g = (ks * 4 + quad) ^ (row & 7);
                bfr[nt] = *(const bf16x8_t*)&Bs[row * 64 + g * 8];
            }
            #pragma unroll
            for (int mt = 0; mt < 4; ++mt)
                #pragma unroll
                for (int nt = 0; nt < 4; ++nt)
                    acc[mt][nt] = __builtin_amdgcn_mfma_f32_16x16x32_bf16(af[mt], bfr[nt],
                                                                          acc[mt][nt], 0, 0, 0);
        }
    }

    float bvv[4];
    #pragma unroll
    for (int nt = 0; nt < 4; ++nt) bvv[nt] = bias[n0 + wn * 64 + nt * 16 + l15];
    #pragma unroll
    for (int mt = 0; mt < 4; ++mt)
        #pragma unroll
        for (int nt = 0; nt < 4; ++nt)
            #pragma unroll
            for (int r = 0; r < 4; ++r) {
                int row = m0 + wm * 64 + mt * 16 + quad * 4 + r;
                int col = n0 + wn * 64 + nt * 16 + l15;
                float v = acc[mt][nt][r] + bvv[nt];
                if (RELU) v = fmaxf(v, 0.f);
                C[(size_t)row * N + col] = f2b(v);
            }
}

// ---------------- scores via skinny MFMA: scb[b][h][l] = C1[t,:] . wv2[:,h] + ck2[h]
// block = 64 tokens (4 waves x one 16-token m-tile); wv2t staged in LDS (64 KB)
__global__ __launch_bounds__(256) void score2_kernel(const u16* __restrict__ C1,
                                                     const u16* __restrict__ wv2t,
                                                     const float* __restrict__ ck2,
                                                     float* __restrict__ scb) {
    __shared__ __align__(16) u16 bsh[16 * 2048];
    const int tid = threadIdx.x;
    const int w = tid >> 6, lane = tid & 63, quad = lane >> 4, l15 = lane & 15;
    for (int i = tid; i < 4096; i += 256)
        ((float4*)bsh)[i] = ((const float4*)wv2t)[i];
    __syncthreads();
    const int m0 = blockIdx.x * 64 + w * 16;
    const u16* arow = C1 + (size_t)(m0 + l15) * 2048 + quad * 8;
    const u16* brow = &bsh[l15 * 2048 + quad * 8];
    f32x4 acc = {};
    #pragma unroll 4
    for (int kt = 0; kt < 64; ++kt) {
        bf16x8_t af = *(const bf16x8_t*)(arow + kt * 32);
        bf16x8_t bf = *(const bf16x8_t*)(brow + kt * 32);
        acc = __builtin_amdgcn_mfma_f32_16x16x32_bf16(af, bf, acc, 0, 0, 0);
    }
    if (l15 < 8) {
        float ck = ck2[l15];
        #pragma unroll
        for (int r = 0; r < 4; ++r) {
            int t = m0 + quad * 4 + r;
            scb[((size_t)(t >> 10) * 8 + l15) * 1024 + (t & 1023)] = acc[r] + ck;
        }
    }
}

// ---------------- softmax over l for each (b,h); in-place on scb. grid 512.
__global__ __launch_bounds__(256) void softmax_kernel(float* __restrict__ scb) {
    __shared__ float red[8];
    const int bh = blockIdx.x, tid = threadIdx.x;
    const int w = tid >> 6, lane = tid & 63;
    float* p = scb + (size_t)bh * 1024;
    float4 v = ((float4*)p)[tid];
    float m = fmaxf(fmaxf(v.x, v.y), fmaxf(v.z, v.w));
    for (int off = 32; off; off >>= 1) m = fmaxf(m, __shfl_xor(m, off, 64));
    if (lane == 0) red[w] = m;
    __syncthreads();
    m = fmaxf(fmaxf(red[0], red[1]), fmaxf(red[2], red[3]));
    float4 e;
    e.x = __expf(v.x - m); e.y = __expf(v.y - m);
    e.z = __expf(v.z - m); e.w = __expf(v.w - m);
    float s = e.x + e.y + e.z + e.w;
    for (int off = 32; off; off >>= 1) s += __shfl_xor(s, off, 64);
    __syncthreads();
    if (lane == 0) red[4 + w] = s;
    __syncthreads();
    float inv = 1.f / (red[4] + red[5] + red[6] + red[7]);
    e.x *= inv; e.y *= inv; e.z *= inv; e.w *= inv;
    ((float4*)p)[tid] = e;
}

// ---------------- g1 partials: pbuf[b][c][h][k] = sum_{l in chunk} a[b,h,l]*C1[l,k]
// grid (NC_, B_); wave w owns dim-slice w*512; lane owns 8 dims.
__global__ __launch_bounds__(256) void wsum2_kernel(const u16* __restrict__ C1,
                                                    const float* __restrict__ scb,
                                                    float* __restrict__ pbuf) {
    __shared__ float as[8][L_ / NC_];
    const int b = blockIdx.y, c = blockIdx.x, tid = threadIdx.x;
    const int w = tid >> 6, lane = tid & 63;
    const int CL = L_ / NC_;   // 128
    for (int i = tid; i < 8 * CL; i += 256) {
        int hh = i / CL, l = i % CL;
        as[hh][l] = scb[((size_t)b * 8 + hh) * 1024 + c * CL + l];
    }
    __syncthreads();
    const u16* hb = C1 + ((size_t)(b * 1024 + c * CL)) * 2048 + w * 512 + lane * 8;
    float acc[8][8] = {};
    for (int l = 0; l < CL; ++l) {
        u16x8 hv = *(const u16x8*)(hb + (size_t)l * 2048);
        float av[8];
        #pragma unroll
        for (int hh = 0; hh < 8; ++hh) av[hh] = as[hh][l];
        #pragma unroll
        for (int j = 0; j < 8; ++j) {
            float hf = b2f(hv[j]);
            #pragma unroll
            for (int hh = 0; hh < 8; ++hh) acc[hh][j] += av[hh] * hf;
        }
    }
    float* pw = pbuf + (((size_t)b * NC_ + c) * 8) * 2048 + w * 512 + lane * 8;
    #pragma unroll
    for (int hh = 0; hh < 8; ++hh) {
        float4 lo, hi;
        lo.x = acc[hh][0]; lo.y = acc[hh][1]; lo.z = acc[hh][2]; lo.w = acc[hh][3];
        hi.x = acc[hh][4]; hi.y = acc[hh][5]; hi.z = acc[hh][6]; hi.w = acc[hh][7];
        *(float4*)(pw + (size_t)hh * 2048) = lo;
        *(float4*)(pw + (size_t)hh * 2048 + 4) = hi;
    }
}

// ---------------- ctx partials: ctxp[b][kc][e] = sum_{k in kc-chunk} g1[b,h(e),k]*WW[k][e]
__global__ __launch_bounds__(256) void ctx_kernel(const float* __restrict__ pbuf,
                                                  const float* __restrict__ WW,
                                                  float* __restrict__ ctxp) {
    __shared__ float g1c[8 * 512];
    const int kc = blockIdx.x, b = blockIdx.y, tid = threadIdx.x;
    for (int i = tid; i < 4096; i += 256) {
        int hh = i >> 9, k = i & 511;
        float s = 0.f;
        #pragma unroll
        for (int c = 0; c < NC_; ++c)
            s += pbuf[(((size_t)b * NC_ + c) * 8 + hh) * 2048 + kc * 512 + k];
        g1c[hh * 512 + k] = s;
    }
    __syncthreads();
    const int e1 = tid, e2 = tid + 256;
    const int h1 = e1 >> 6, h2 = e2 >> 6;
    float a1 = 0.f, a2 = 0.f;
    for (int k = 0; k < 512; k += 4) {
        float4 g1v = *(const float4*)&g1c[h1 * 512 + k];
        float4 g2v = *(const float4*)&g1c[h2 * 512 + k];
        const float* wr = WW + (size_t)(kc * 512 + k) * 512;
        a1 += g1v.x * wr[e1] + g1v.y * wr[512 + e1] + g1v.z * wr[1024 + e1] + g1v.w * wr[1536 + e1];
        a2 += g2v.x * wr[e2] + g2v.y * wr[512 + e2] + g2v.z * wr[1024 + e2] + g2v.w * wr[1536 + e2];
    }
    ctxp[((size_t)b * 4 + kc) * 512 + e1] = a1;
    ctxp[((size_t)b * 4 + kc) * 512 + e2] = a2;
}

// ---------------- per-set: ctx fold + pooled = ctx@Wo + bo; LN -> y
__global__ __launch_bounds__(256) void pool2_kernel(const float* __restrict__ ctxp,
                                                    const float* __restrict__ cvv,
                                                    const float* __restrict__ Wo,
                                                    const float* __restrict__ bo,
                                                    const float* __restrict__ g,
                                                    const float* __restrict__ lb,
                                                    float* __restrict__ y) {
    __shared__ float ctx[512];
    __shared__ float red[8];
    __shared__ float stats[2];
    const int b = blockIdx.x, tid = threadIdx.x;
    for (int i = tid; i < 512; i += 256) {
        float s = cvv[i];
        #pragma unroll
        for (int kc = 0; kc < 4; ++kc) s += ctxp[((size_t)b * 4 + kc) * 512 + i];
        ctx[i] = s;
    }
    __syncthreads();
    float pv[2]; float psum = 0.f, psq = 0.f;
    #pragma unroll
    for (int ph = 0; ph < 2; ++ph) {
        int e2 = tid + ph * 256;
        float acc = bo[e2];
        for (int ee = 0; ee < 512; ++ee) acc += ctx[ee] * Wo[(size_t)ee * 512 + e2];
        pv[ph] = acc; psum += acc; psq += acc * acc;
    }
    for (int off = 32; off; off >>= 1) { psum += __shfl_xor(psum, off, 64); psq += __shfl_xor(psq, off, 64); }
    const int w = tid >> 6, lane = tid & 63;
    if (lane == 0) { red[w] = psum; red[4 + w] = psq; }
    __syncthreads();
    if (tid == 0) {
        float s = red[0] + red[1] + red[2] + red[3];
        float q2 = red[4] + red[5] + red[6] + red[7];
        float mu = s / 512.f;
        float var = q2 / 512.f - mu * mu;
        stats[0] = mu; stats[1] = 1.f / sqrtf(var + 1e-5f);
    }
    __syncthreads();
    #pragma unroll
    for (int ph = 0; ph < 2; ++ph) {
        int e2 = tid + ph * 256;
        y[(size_t)b * 512 + e2] = (pv[ph] - stats[0]) * stats[1] * g[e2] + lb[e2];
    }
}

// ---------------- head MLP layer 1: hid = relu(y@Wh1 + bh1)
__global__ __launch_bounds__(256) void h1_kernel(const float* __restrict__ y,
                                                 const float* __restrict__ Wh1,
                                                 const float* __restrict__ bh1,
                                                 float* __restrict__ hid) {
    __shared__ float ys[512];
    const int b = blockIdx.y, tid = threadIdx.x;
    ys[tid] = y[(size_t)b * 512 + tid];
    ys[tid + 256] = y[(size_t)b * 512 + tid + 256];
    __syncthreads();
    int j = blockIdx.x * 256 + tid;
    float acc = bh1[j];
    for (int dd = 0; dd < 512; ++dd) acc += ys[dd] * Wh1[(size_t)dd * 2048 + j];
    hid[(size_t)b * 2048 + j] = fmaxf(acc, 0.f);
}

// ---------------- head MLP layer 2: logits = hid@Wh2 + bh2
__global__ __launch_bounds__(256) void h2_kernel(const float* __restrict__ hid,
                                                 const float* __restrict__ Wh2,
                                                 const float* __restrict__ bh2,
                                                 float* __restrict__ out) {
    __shared__ float red[4];
    const int b = blockIdx.x, tid = threadIdx.x;
    float s = 0.f;
    for (int j = tid; j < 2048; j += 256) s += hid[(size_t)b * 2048 + j] * Wh2[j];
    for (int off = 32; off; off >>= 1) s += __shfl_xor(s, off, 64);
    const int w = tid >> 6, lane = tid & 63;
    if (lane == 0) red[w] = s;
    __syncthreads();
    if (tid == 0) out[b] = red[0] + red[1] + red[2] + red[3] + bh2[0];
}

extern "C" void kernel_launch(void* const* d_in, const int* in_sizes, int n_in,
                              void* d_out, int out_size, void* d_ws, size_t ws_size,
                              hipStream_t stream) {
    const int*   mut_idx = (const int*)d_in[0];
    const float* emb  = (const float*)d_in[2];
    const float* W1   = (const float*)d_in[3];
    const float* b1   = (const float*)d_in[4];
    const float* W2   = (const float*)d_in[5];
    const float* b2   = (const float*)d_in[6];
    const float* q    = (const float*)d_in[7];
    const float* Wq   = (const float*)d_in[8];
    const float* bq   = (const float*)d_in[9];
    const float* Wk   = (const float*)d_in[10];
    const float* bk   = (const float*)d_in[11];
    const float* Wv   = (const float*)d_in[12];
    const float* bv   = (const float*)d_in[13];
    const float* Wo   = (const float*)d_in[14];
    const float* bo   = (const float*)d_in[15];
    const float* ln_g = (const float*)d_in[16];
    const float* ln_b = (const float*)d_in[17];
    const float* Wh1  = (const float*)d_in[18];
    const float* bh1  = (const float*)d_in[19];
    const float* Wh2  = (const float*)d_in[20];
    const float* bh2  = (const float*)d_in[21];
    float* out = (float*)d_out;

    // workspace layout (256B aligned)
    char* p = (char*)d_ws;
    auto alloc = [&](size_t bytes) {
        char* r = p; p += (bytes + 255) & ~(size_t)255; return r;
    };
    u16*  W1t  = (u16*)alloc((size_t)H_ * D_ * 2);              // 2 MB
    u16*  wv2t = (u16*)alloc((size_t)16 * H_ * 2);              // 64 KB
    float* WW  = (float*)alloc((size_t)H_ * D_ * 4);            // 4 MB
    float* qp  = (float*)alloc(D_ * 4);
    float* wke = (float*)alloc((size_t)D_ * NH_ * 4);
    float* cke = (float*)alloc(NH_ * 4);
    float* ck2 = (float*)alloc(NH_ * 4);
    float* cvv = (float*)alloc(D_ * 4);
    float* scb  = (float*)alloc((size_t)B_ * NH_ * L_ * 4);     // 2 MB
    float* pbuf = (float*)alloc((size_t)B_ * NC_ * NH_ * H_ * 4); // 33.5 MB
    float* ctxp = (float*)alloc((size_t)B_ * 4 * D_ * 4);       // 512 KB
    float* ybuf = (float*)alloc((size_t)B_ * D_ * 4);
    float* hid  = (float*)alloc((size_t)B_ * H_ * 4);
    u16*  z    = (u16*)alloc((size_t)TOT * D_ * 2);             // 67 MB
    u16*  C1   = (u16*)alloc((size_t)TOT * H_ * 2);             // 268 MB

    // setup / weight folding
    transpose_cvt<<<dim3(H_ / 32, D_ / 32), dim3(32, 8), 0, stream>>>(W1, W1t, D_, H_);
    qp_kernel<<<2, 256, 0, stream>>>(q, Wq, bq, qp);
    wke_kernel<<<16, 256, 0, stream>>>(Wk, bk, qp, wke, cke);
    wv2_kernel<<<64, 256, 0, stream>>>(W2, wke, cke, b2, wv2t, ck2);
    cvv_kernel<<<2, 256, 0, stream>>>(Wv, b2, bv, cvv);
    ww_kernel<<<dim3(8, 32), 256, 0, stream>>>(W2, Wv, WW);

    // phi layer-1 only (layer-2 algebraically folded away)
    embed_kernel<<<TOT / 4, 256, 0, stream>>>(mut_idx, emb, z);
    gemm_bt256<1, 4><<<dim3((TOT / 256) * 16), 512, 0, stream>>>(z, W1t, b1, C1, H_, D_);

    // attention pool on C1 + folded tail
    score2_kernel<<<TOT / 64, 256, 0, stream>>>(C1, wv2t, ck2, scb);
    softmax_kernel<<<B_ * NH_, 256, 0, stream>>>(scb);
    wsum2_kernel<<<dim3(NC_, B_), 256, 0, stream>>>(C1, scb, pbuf);
    ctx_kernel<<<dim3(4, B_), 256, 0, stream>>>(pbuf, WW, ctxp);
    pool2_kernel<<<B_, 256, 0, stream>>>(ctxp, cvv, Wo, bo, ln_g, ln_b, ybuf);
    h1_kernel<<<dim3(H_ / 256, B_), 256, 0, stream>>>(ybuf, Wh1, bh1, hid);
    h2_kernel<<<B_, 256, 0, stream>>>(hid, Wh2, bh2, out);
}

// Round 7
// 832.120 us; speedup vs baseline: 1.1417x; 1.0016x over previous
//
#include <hip/hip_runtime.h>
#include <hip/hip_bf16.h>

using u16 = unsigned short;
typedef __bf16 bf16x8_t __attribute__((ext_vector_type(8)));
typedef float    f32x4  __attribute__((ext_vector_type(4)));
typedef unsigned short u16x8 __attribute__((ext_vector_type(8)));

#define B_  64
#define L_  1024
#define TOT 65536
#define D_  512
#define H_  2048
#define NH_ 8
#define NC_ 16   // l-chunks of 64 tokens for fused attention pass

__device__ __forceinline__ float b2f(u16 x) {
    union { unsigned int i; float f; } v; v.i = ((unsigned int)x) << 16; return v.f;
}
__device__ __forceinline__ u16 f2b(float f) {
    union { float f; unsigned int i; } v; v.f = f;
    unsigned int i = v.i;
    unsigned int r = i + 0x7FFFu + ((i >> 16) & 1u);   // RNE
    return (u16)(r >> 16);
}

// ---------------- transpose + fp32->bf16 convert:  in[R][C] f32 -> out[C][R] bf16
__global__ __launch_bounds__(256) void transpose_cvt(const float* __restrict__ in,
                                                     u16* __restrict__ out, int R, int C) {
    __shared__ float tile[32][33];
    int c0 = blockIdx.x * 32, r0 = blockIdx.y * 32;
    int tx = threadIdx.x, ty = threadIdx.y;
    #pragma unroll
    for (int i = 0; i < 4; ++i)
        tile[ty + 8 * i][tx] = in[(size_t)(r0 + ty + 8 * i) * C + c0 + tx];
    __syncthreads();
    #pragma unroll
    for (int i = 0; i < 4; ++i)
        out[(size_t)(c0 + ty + 8 * i) * R + r0 + tx] = f2b(tile[tx][ty + 8 * i]);
}

// ---------------- qp = q @ Wq + bq
__global__ __launch_bounds__(256) void qp_kernel(const float* __restrict__ q,
                                                 const float* __restrict__ Wq,
                                                 const float* __restrict__ bq,
                                                 float* __restrict__ qp) {
    __shared__ float qs[512];
    int tid = threadIdx.x;
    qs[tid] = q[tid]; qs[tid + 256] = q[tid + 256];
    __syncthreads();
    int j = blockIdx.x * 256 + tid;
    float acc = bq[j];
    for (int d = 0; d < 512; ++d) acc += qs[d] * Wq[(size_t)d * 512 + j];
    qp[j] = acc;
}

// ---------------- wke[d][h] = 0.125*sum_j Wk[d,h*64+j]*qp[h*64+j];  cke[h] from bk
__global__ __launch_bounds__(256) void wke_kernel(const float* __restrict__ Wk,
                                                  const float* __restrict__ bk,
                                                  const float* __restrict__ qp,
                                                  float* __restrict__ wke,
                                                  float* __restrict__ cke) {
    __shared__ float qs[512];
    int tid = threadIdx.x;
    qs[tid] = qp[tid]; qs[tid + 256] = qp[tid + 256];
    __syncthreads();
    int d = blockIdx.x * 32 + (tid >> 3);
    int h = tid & 7;
    float s = 0.f;
    for (int j = 0; j < 64; ++j) s += Wk[(size_t)d * 512 + h * 64 + j] * qs[h * 64 + j];
    wke[d * 8 + h] = 0.125f * s;
    if (blockIdx.x == 0 && tid < 8) {
        float c = 0.f;
        for (int j = 0; j < 64; ++j) c += bk[tid * 64 + j] * qs[tid * 64 + j];
        cke[tid] = 0.125f * c;
    }
}

// ---------------- wv2t[h][k] = bf16( sum_d W2[k][d]*wke[d][h] ), rows 8..15 zero.
// ck2[h] = sum_d b2[d]*wke[d][h] + cke[h]
__global__ __launch_bounds__(256) void wv2_kernel(const float* __restrict__ W2,
                                                  const float* __restrict__ wke,
                                                  const float* __restrict__ cke,
                                                  const float* __restrict__ b2,
                                                  u16* __restrict__ wv2t,
                                                  float* __restrict__ ck2) {
    __shared__ float wk[512 * 8];
    int tid = threadIdx.x;
    for (int i = tid; i < 4096; i += 256) wk[i] = wke[i];
    __syncthreads();
    int k = blockIdx.x * 32 + (tid >> 3);
    int h = tid & 7;
    float s = 0.f;
    const float* row = W2 + (size_t)k * 512;
    for (int d = 0; d < 512; ++d) s += row[d] * wk[d * 8 + h];
    wv2t[(size_t)h * 2048 + k] = f2b(s);
    wv2t[(size_t)(h + 8) * 2048 + k] = 0;
    if (blockIdx.x == 0 && tid < 8) {
        float c = 0.f;
        for (int d = 0; d < 512; ++d) c += b2[d] * wk[d * 8 + tid];
        ck2[tid] = c + cke[tid];
    }
}

// ---------------- cvv[e] = sum_d b2[d]*Wv[d][e] + bv[e]
__global__ __launch_bounds__(256) void cvv_kernel(const float* __restrict__ Wv,
                                                  const float* __restrict__ b2,
                                                  const float* __restrict__ bv,
                                                  float* __restrict__ cvv) {
    int e = blockIdx.x * 256 + threadIdx.x;
    float s = bv[e];
    for (int d = 0; d < 512; ++d) s += b2[d] * Wv[(size_t)d * 512 + e];
    cvv[e] = s;
}

// ---------------- WW[2048][512] = W2[2048][512] @ Wv[512][512]  (fp32 tiled)
__global__ __launch_bounds__(256) void ww_kernel(const float* __restrict__ W2,
                                                 const float* __restrict__ Wv,
                                                 float* __restrict__ WW) {
    __shared__ float As[64][65];
    __shared__ float Bs[64][65];
    const int m0 = blockIdx.y * 64, n0 = blockIdx.x * 64;
    const int tid = threadIdx.x;
    const int tx = tid & 15, ty = tid >> 4;
    float acc[4][4] = {};
    for (int k0 = 0; k0 < 512; k0 += 64) {
        for (int i = tid; i < 4096; i += 256) {
            int r = i >> 6, c = i & 63;
            As[r][c] = W2[(size_t)(m0 + r) * 512 + k0 + c];
            Bs[r][c] = Wv[(size_t)(k0 + r) * 512 + n0 + c];
        }
        __syncthreads();
        for (int kk = 0; kk < 64; ++kk) {
            float a[4], b[4];
            #pragma unroll
            for (int i = 0; i < 4; ++i) a[i] = As[ty * 4 + i][kk];
            #pragma unroll
            for (int j = 0; j < 4; ++j) b[j] = Bs[kk][tx * 4 + j];
            #pragma unroll
            for (int i = 0; i < 4; ++i)
                #pragma unroll
                for (int j = 0; j < 4; ++j) acc[i][j] += a[i] * b[j];
        }
        __syncthreads();
    }
    #pragma unroll
    for (int i = 0; i < 4; ++i)
        #pragma unroll
        for (int j = 0; j < 4; ++j)
            WW[(size_t)(m0 + ty * 4 + i) * 512 + n0 + tx * 4 + j] = acc[i][j];
}

// ---------------- gather emb rows -> bf16 z
__global__ __launch_bounds__(256) void embed_kernel(const int* __restrict__ idx,
                                                    const float* __restrict__ emb,
                                                    u16* __restrict__ z) {
    int u = blockIdx.x * 256 + threadIdx.x;   // one unit = 8 elements
    int t = u >> 6;
    int d0 = (u & 63) * 8;
    int row = idx[t];
    const float4* src = (const float4*)(emb + (size_t)row * 512 + d0);
    float4 a = src[0], b = src[1];
    u16x8 o;
    o[0] = f2b(a.x); o[1] = f2b(a.y); o[2] = f2b(a.z); o[3] = f2b(a.w);
    o[4] = f2b(b.x); o[5] = f2b(b.y); o[6] = f2b(b.z); o[7] = f2b(b.w);
    *(u16x8*)(z + (size_t)t * 512 + d0) = o;
}

// ---------------- bf16 GEMM 256x128, BK=64, 8 waves: C = relu(A@Bt^T + bias)
template <int RELU, int LNT>
__global__ __launch_bounds__(512) void gemm_bt256(const u16* __restrict__ A,
                                                  const u16* __restrict__ Bt,
                                                  const float* __restrict__ bias,
                                                  u16* __restrict__ C,
                                                  int N, int K) {
    __shared__ __align__(16) u16 As[256 * 64];
    __shared__ __align__(16) u16 Bs[128 * 64];
    const int tid = threadIdx.x;
    const int id = blockIdx.x;
    const int xcd = id & 7, s = id >> 3;
    const int n_idx = s & ((1 << LNT) - 1);
    const int m_idx = xcd + 8 * (s >> LNT);
    const int m0 = m_idx * 256, n0 = n_idx * 128;
    const int lane = tid & 63, quad = lane >> 4, l15 = lane & 15;
    const int wave = tid >> 6, wm = wave >> 1, wn = wave & 1;

    f32x4 acc[4][4] = {};

    const int nK = K >> 6;
    for (int kt = 0; kt < nK; ++kt) {
        __syncthreads();
        const int kb = kt * 64;
        #pragma unroll
        for (int r = 0; r < 4; ++r) {
            int u = tid + r * 512;
            int row = u >> 3;
            int cg = (u & 7) ^ (row & 7);
            const u16* ga = A + (size_t)(m0 + row) * K + kb + cg * 8;
            __builtin_amdgcn_global_load_lds((const __attribute__((address_space(1))) void*)ga,
                                             (__attribute__((address_space(3))) void*)(&As[u * 8]),
                                             16, 0, 0);
        }
        #pragma unroll
        for (int r = 0; r < 2; ++r) {
            int u = tid + r * 512;
            int row = u >> 3;
            int cg = (u & 7) ^ (row & 7);
            const u16* gb = Bt + (size_t)(n0 + row) * K + kb + cg * 8;
            __builtin_amdgcn_global_load_lds((const __attribute__((address_space(1))) void*)gb,
                                             (__attribute__((address_space(3))) void*)(&Bs[u * 8]),
                                             16, 0, 0);
        }
        __syncthreads();
        #pragma unroll
        for (int ks = 0; ks < 2; ++ks) {
            bf16x8_t af[4], bfr[4];
            #pragma unroll
            for (int mt = 0; mt < 4; ++mt) {
                int row = wm * 64 + mt * 16 + l15;
                int g = (ks * 4 + quad) ^ (row & 7);
                af[mt] = *(const bf16x8_t*)&As[row * 64 + g * 8];
            }
            #pragma unroll
            for (int nt = 0; nt < 4; ++nt) {
                int row = wn * 64 + nt * 16 + l15;
                int g = (ks * 4 + quad) ^ (row & 7);
                bfr[nt] = *(const bf16x8_t*)&Bs[row * 64 + g * 8];
            }
            #pragma unroll
            for (int mt = 0; mt < 4; ++mt)
                #pragma unroll
                for (int nt = 0; nt < 4; ++nt)
                    acc[mt][nt] = __builtin_amdgcn_mfma_f32_16x16x32_bf16(af[mt], bfr[nt],
                                                                          acc[mt][nt], 0, 0, 0);
        }
    }

    float bvv[4];
    #pragma unroll
    for (int nt = 0; nt < 4; ++nt) bvv[nt] = bias[n0 + wn * 64 + nt * 16 + l15];
    #pragma unroll
    for (int mt = 0; mt < 4; ++mt)
        #pragma unroll
        for (int nt = 0; nt < 4; ++nt)
            #pragma unroll
            for (int r = 0; r < 4; ++r) {
                int row = m0 + wm * 64 + mt * 16 + quad * 4 + r;
                int col = n0 + wn * 64 + nt * 16 + l15;
                float v = acc[mt][nt][r] + bvv[nt];
                if (RELU) v = fmaxf(v, 0.f);
                C[(size_t)row * N + col] = f2b(v);
            }
}

// ---------------- fused flash-style attention pool over 64-token chunks.
// Phase 1: scores for the chunk via MFMA (wv2t staged in LDS).
// Chunk softmax partials: m_c[h], p = exp(s-m_c), s_c[h].
// Phase 2: g1 partial = sum_l p[l][h]*C1[l][k] (C1 chunk is L2-hot from phase 1).
// Fold across chunks (with exp(m_c-m)/denom rescale) happens in ctx_kernel.
__global__ __launch_bounds__(256) void attn2_kernel(const u16* __restrict__ C1,
                                                    const u16* __restrict__ wv2t,
                                                    const float* __restrict__ ck2,
                                                    float* __restrict__ pbuf,
                                                    float* __restrict__ msbuf) {
    __shared__ __align__(16) u16 bsh[16 * 2048];   // 64 KB
    __shared__ float sc[64][8];                    // raw scores
    __shared__ float pp[64][8];                    // exp(s - m_c)
    __shared__ float mh[8];
    const int c = blockIdx.x, b = blockIdx.y, tid = threadIdx.x;
    const int w = tid >> 6, lane = tid & 63, quad = lane >> 4, l15 = lane & 15;

    for (int i = tid; i < 4096; i += 256)
        ((float4*)bsh)[i] = ((const float4*)wv2t)[i];
    __syncthreads();

    const int t0 = b * 1024 + c * 64;         // chunk token base
    // --- phase 1: wave w scores tokens t0 + w*16 .. +15
    {
        const u16* arow = C1 + (size_t)(t0 + w * 16 + l15) * 2048 + quad * 8;
        const u16* brow = &bsh[l15 * 2048 + quad * 8];
        f32x4 acc = {};
        #pragma unroll 4
        for (int kt = 0; kt < 64; ++kt) {
            bf16x8_t af = *(const bf16x8_t*)(arow + kt * 32);
            bf16x8_t bf = *(const bf16x8_t*)(brow + kt * 32);
            acc = __builtin_amdgcn_mfma_f32_16x16x32_bf16(af, bf, acc, 0, 0, 0);
        }
        if (l15 < 8) {
            float ck = ck2[l15];
            #pragma unroll
            for (int r = 0; r < 4; ++r)
                sc[w * 16 + quad * 4 + r][l15] = acc[r] + ck;
        }
    }
    __syncthreads();
    // --- chunk max per head
    if (tid < 8) {
        float m = -1e30f;
        for (int l = 0; l < 64; ++l) m = fmaxf(m, sc[l][tid]);
        mh[tid] = m;
    }
    __syncthreads();
    for (int i = tid; i < 512; i += 256) {
        int l = i >> 3, h = i & 7;
        pp[l][h] = __expf(sc[l][h] - mh[h]);
    }
    __syncthreads();
    if (tid < 8) {
        float s = 0.f;
        for (int l = 0; l < 64; ++l) s += pp[l][tid];
        float* mb = msbuf + ((size_t)b * NC_ + c) * 16;
        mb[tid] = mh[tid];
        mb[8 + tid] = s;
    }
    // --- phase 2: wave w owns cols [w*512, w*512+512); lane owns 8 cols
    const u16* crow = C1 + (size_t)t0 * 2048 + w * 512 + lane * 8;
    float acc2[8][8] = {};
    for (int l = 0; l < 64; ++l) {
        u16x8 v = *(const u16x8*)(crow + (size_t)l * 2048);
        float av[8];
        #pragma unroll
        for (int hh = 0; hh < 8; ++hh) av[hh] = pp[l][hh];
        #pragma unroll
        for (int j = 0; j < 8; ++j) {
            float hf = b2f(v[j]);
            #pragma unroll
            for (int hh = 0; hh < 8; ++hh) acc2[hh][j] += av[hh] * hf;
        }
    }
    float* pw = pbuf + (((size_t)b * NC_ + c) * 8) * 2048 + w * 512 + lane * 8;
    #pragma unroll
    for (int hh = 0; hh < 8; ++hh) {
        float4 lo, hi;
        lo.x = acc2[hh][0]; lo.y = acc2[hh][1]; lo.z = acc2[hh][2]; lo.w = acc2[hh][3];
        hi.x = acc2[hh][4]; hi.y = acc2[hh][5]; hi.z = acc2[hh][6]; hi.w = acc2[hh][7];
        *(float4*)(pw + (size_t)hh * 2048) = lo;
        *(float4*)(pw + (size_t)hh * 2048 + 4) = hi;
    }
}

// ---------------- ctx partials with flash fold:
// scale_c[h] = exp(m_c-m)/denom;  g1[h][k] = sum_c pbuf*scale;  ctxp = g1 @ WW (kc slice)
__global__ __launch_bounds__(256) void ctx_kernel(const float* __restrict__ pbuf,
                                                  const float* __restrict__ msbuf,
                                                  const float* __restrict__ WW,
                                                  float* __restrict__ ctxp) {
    __shared__ float g1c[8 * 512];
    __shared__ float scl[NC_ * 8];
    const int kc = blockIdx.x, b = blockIdx.y, tid = threadIdx.x;
    if (tid < 8) {
        const float* mb = msbuf + (size_t)b * NC_ * 16;
        float m = -1e30f;
        for (int c = 0; c < NC_; ++c) m = fmaxf(m, mb[c * 16 + tid]);
        float den = 0.f;
        for (int c = 0; c < NC_; ++c) den += mb[c * 16 + 8 + tid] * __expf(mb[c * 16 + tid] - m);
        float inv = 1.f / den;
        for (int c = 0; c < NC_; ++c) scl[c * 8 + tid] = __expf(mb[c * 16 + tid] - m) * inv;
    }
    __syncthreads();
    for (int i = tid; i < 4096; i += 256) {
        int hh = i >> 9, k = i & 511;
        float s = 0.f;
        #pragma unroll
        for (int c = 0; c < NC_; ++c)
            s += pbuf[(((size_t)b * NC_ + c) * 8 + hh) * 2048 + kc * 512 + k] * scl[c * 8 + hh];
        g1c[hh * 512 + k] = s;
    }
    __syncthreads();
    const int e1 = tid, e2 = tid + 256;
    const int h1 = e1 >> 6, h2 = e2 >> 6;
    float a1 = 0.f, a2 = 0.f;
    for (int k = 0; k < 512; k += 4) {
        float4 g1v = *(const float4*)&g1c[h1 * 512 + k];
        float4 g2v = *(const float4*)&g1c[h2 * 512 + k];
        const float* wr = WW + (size_t)(kc * 512 + k) * 512;
        a1 += g1v.x * wr[e1] + g1v.y * wr[512 + e1] + g1v.z * wr[1024 + e1] + g1v.w * wr[1536 + e1];
        a2 += g2v.x * wr[e2] + g2v.y * wr[512 + e2] + g2v.z * wr[1024 + e2] + g2v.w * wr[1536 + e2];
    }
    ctxp[((size_t)b * 4 + kc) * 512 + e1] = a1;
    ctxp[((size_t)b * 4 + kc) * 512 + e2] = a2;
}

// ---------------- per-set: ctx fold + pooled = ctx@Wo + bo; LN -> y
__global__ __launch_bounds__(256) void pool2_kernel(const float* __restrict__ ctxp,
                                                    const float* __restrict__ cvv,
                                                    const float* __restrict__ Wo,
                                                    const float* __restrict__ bo,
                                                    const float* __restrict__ g,
                                                    const float* __restrict__ lb,
                                                    float* __restrict__ y) {
    __shared__ float ctx[512];
    __shared__ float red[8];
    __shared__ float stats[2];
    const int b = blockIdx.x, tid = threadIdx.x;
    for (int i = tid; i < 512; i += 256) {
        float s = cvv[i];
        #pragma unroll
        for (int kc = 0; kc < 4; ++kc) s += ctxp[((size_t)b * 4 + kc) * 512 + i];
        ctx[i] = s;
    }
    __syncthreads();
    float pv[2]; float psum = 0.f, psq = 0.f;
    #pragma unroll
    for (int ph = 0; ph < 2; ++ph) {
        int e2 = tid + ph * 256;
        float acc = bo[e2];
        for (int ee = 0; ee < 512; ++ee) acc += ctx[ee] * Wo[(size_t)ee * 512 + e2];
        pv[ph] = acc; psum += acc; psq += acc * acc;
    }
    for (int off = 32; off; off >>= 1) { psum += __shfl_xor(psum, off, 64); psq += __shfl_xor(psq, off, 64); }
    const int w = tid >> 6, lane = tid & 63;
    if (lane == 0) { red[w] = psum; red[4 + w] = psq; }
    __syncthreads();
    if (tid == 0) {
        float s = red[0] + red[1] + red[2] + red[3];
        float q2 = red[4] + red[5] + red[6] + red[7];
        float mu = s / 512.f;
        float var = q2 / 512.f - mu * mu;
        stats[0] = mu; stats[1] = 1.f / sqrtf(var + 1e-5f);
    }
    __syncthreads();
    #pragma unroll
    for (int ph = 0; ph < 2; ++ph) {
        int e2 = tid + ph * 256;
        y[(size_t)b * 512 + e2] = (pv[ph] - stats[0]) * stats[1] * g[e2] + lb[e2];
    }
}

// ---------------- head MLP layer 1: hid = relu(y@Wh1 + bh1)
__global__ __launch_bounds__(256) void h1_kernel(const float* __restrict__ y,
                                                 const float* __restrict__ Wh1,
                                                 const float* __restrict__ bh1,
                                                 float* __restrict__ hid) {
    __shared__ float ys[512];
    const int b = blockIdx.y, tid = threadIdx.x;
    ys[tid] = y[(size_t)b * 512 + tid];
    ys[tid + 256] = y[(size_t)b * 512 + tid + 256];
    __syncthreads();
    int j = blockIdx.x * 256 + tid;
    float acc = bh1[j];
    for (int dd = 0; dd < 512; ++dd) acc += ys[dd] * Wh1[(size_t)dd * 2048 + j];
    hid[(size_t)b * 2048 + j] = fmaxf(acc, 0.f);
}

// ---------------- head MLP layer 2: logits = hid@Wh2 + bh2
__global__ __launch_bounds__(256) void h2_kernel(const float* __restrict__ hid,
                                                 const float* __restrict__ Wh2,
                                                 const float* __restrict__ bh2,
                                                 float* __restrict__ out) {
    __shared__ float red[4];
    const int b = blockIdx.x, tid = threadIdx.x;
    float s = 0.f;
    for (int j = tid; j < 2048; j += 256) s += hid[(size_t)b * 2048 + j] * Wh2[j];
    for (int off = 32; off; off >>= 1) s += __shfl_xor(s, off, 64);
    const int w = tid >> 6, lane = tid & 63;
    if (lane == 0) red[w] = s;
    __syncthreads();
    if (tid == 0) out[b] = red[0] + red[1] + red[2] + red[3] + bh2[0];
}

extern "C" void kernel_launch(void* const* d_in, const int* in_sizes, int n_in,
                              void* d_out, int out_size, void* d_ws, size_t ws_size,
                              hipStream_t stream) {
    const int*   mut_idx = (const int*)d_in[0];
    const float* emb  = (const float*)d_in[2];
    const float* W1   = (const float*)d_in[3];
    const float* b1   = (const float*)d_in[4];
    const float* W2   = (const float*)d_in[5];
    const float* b2   = (const float*)d_in[6];
    const float* q    = (const float*)d_in[7];
    const float* Wq   = (const float*)d_in[8];
    const float* bq   = (const float*)d_in[9];
    const float* Wk   = (const float*)d_in[10];
    const float* bk   = (const float*)d_in[11];
    const float* Wv   = (const float*)d_in[12];
    const float* bv   = (const float*)d_in[13];
    const float* Wo   = (const float*)d_in[14];
    const float* bo   = (const float*)d_in[15];
    const float* ln_g = (const float*)d_in[16];
    const float* ln_b = (const float*)d_in[17];
    const float* Wh1  = (const float*)d_in[18];
    const float* bh1  = (const float*)d_in[19];
    const float* Wh2  = (const float*)d_in[20];
    const float* bh2  = (const float*)d_in[21];
    float* out = (float*)d_out;

    // workspace layout (256B aligned)
    char* p = (char*)d_ws;
    auto alloc = [&](size_t bytes) {
        char* r = p; p += (bytes + 255) & ~(size_t)255; return r;
    };
    u16*  W1t  = (u16*)alloc((size_t)H_ * D_ * 2);              // 2 MB
    u16*  wv2t = (u16*)alloc((size_t)16 * H_ * 2);              // 64 KB
    float* WW  = (float*)alloc((size_t)H_ * D_ * 4);            // 4 MB
    float* qp  = (float*)alloc(D_ * 4);
    float* wke = (float*)alloc((size_t)D_ * NH_ * 4);
    float* cke = (float*)alloc(NH_ * 4);
    float* ck2 = (float*)alloc(NH_ * 4);
    float* cvv = (float*)alloc(D_ * 4);
    float* pbuf = (float*)alloc((size_t)B_ * NC_ * NH_ * H_ * 4); // 67 MB
    float* msbuf = (float*)alloc((size_t)B_ * NC_ * 16 * 4);    // 64 KB
    float* ctxp = (float*)alloc((size_t)B_ * 4 * D_ * 4);       // 512 KB
    float* ybuf = (float*)alloc((size_t)B_ * D_ * 4);
    float* hid  = (float*)alloc((size_t)B_ * H_ * 4);
    u16*  z    = (u16*)alloc((size_t)TOT * D_ * 2);             // 67 MB
    u16*  C1   = (u16*)alloc((size_t)TOT * H_ * 2);             // 268 MB

    // setup / weight folding
    transpose_cvt<<<dim3(H_ / 32, D_ / 32), dim3(32, 8), 0, stream>>>(W1, W1t, D_, H_);
    qp_kernel<<<2, 256, 0, stream>>>(q, Wq, bq, qp);
    wke_kernel<<<16, 256, 0, stream>>>(Wk, bk, qp, wke, cke);
    wv2_kernel<<<64, 256, 0, stream>>>(W2, wke, cke, b2, wv2t, ck2);
    cvv_kernel<<<2, 256, 0, stream>>>(Wv, b2, bv, cvv);
    ww_kernel<<<dim3(8, 32), 256, 0, stream>>>(W2, Wv, WW);

    // phi layer-1 only (layer-2 algebraically folded away)
    embed_kernel<<<TOT / 4, 256, 0, stream>>>(mut_idx, emb, z);
    gemm_bt256<1, 4><<<dim3((TOT / 256) * 16), 512, 0, stream>>>(z, W1t, b1, C1, H_, D_);

    // fused flash-style attention pool on C1 + folded tail
    attn2_kernel<<<dim3(NC_, B_), 256, 0, stream>>>(C1, wv2t, ck2, pbuf, msbuf);
    ctx_kernel<<<dim3(4, B_), 256, 0, stream>>>(pbuf, msbuf, WW, ctxp);
    pool2_kernel<<<B_, 256, 0, stream>>>(ctxp, cvv, Wo, bo, ln_g, ln_b, ybuf);
    h1_kernel<<<dim3(H_ / 256, B_), 256, 0, stream>>>(ybuf, Wh1, bh1, hid);
    h2_kernel<<<B_, 256, 0, stream>>>(hid, Wh2, bh2, out);
}